// Round 11
// baseline (271.197 us; speedup 1.0000x reference)
//
#include <hip/hip_runtime.h>

typedef unsigned short u16;
typedef unsigned int u32;
typedef short bf16x8 __attribute__((ext_vector_type(8)));
typedef float f32x4 __attribute__((ext_vector_type(4)));
typedef unsigned short u16x4 __attribute__((ext_vector_type(4)));
typedef unsigned short u16x8 __attribute__((ext_vector_type(8)));

__device__ __forceinline__ u16 f32_to_bf16(float f) {
    u32 u = __float_as_uint(f);
    u += 0x7FFFu + ((u >> 16) & 1u);
    return (u16)(u >> 16);
}
// truncating cast (p in [0,1], P-matrix only)
__device__ __forceinline__ short f32_to_bf16_trunc(float f) {
    return (short)(__float_as_uint(f) >> 16);
}

// native exp2 (v_exp_f32); fallback via __expf if builtin missing
#if __has_builtin(__builtin_amdgcn_exp2f)
#define EXP2(x) __builtin_amdgcn_exp2f(x)
#else
#define EXP2(x) __expf((x) * 0.69314718056f)
#endif

// async global->LDS, 16B per lane; lds pointer must be wave-uniform
__device__ __forceinline__ void gl_lds16(const u16* g, u16* l) {
    __builtin_amdgcn_global_load_lds(
        (const __attribute__((address_space(1))) u32*)g,
        (__attribute__((address_space(3))) u32*)l, 16, 0, 0);
}

// Bank-conflict swizzle for 64B-row LDS tiles read as (row*32 + chunk*8) u16:
// physical chunk = logical chunk ^ ((row>>1)&3). Folded into the DMA *source*
// address (per-lane), so LDS writes stay contiguous. Makes each 8-lane phase
// of a ds_read_b128 hit all 8 bank groups (was 4-way conflicted).

// ---------------------------------------------------------------------------
// bulk fp32 -> bf16 cast; slice y==7 builds the RoPE cos/sin tables
// (same __sincosf as the previous in-line epilogue -> bit-identical values).
// ---------------------------------------------------------------------------
struct CastArgs {
    const float* src[8];
    u16* dst[8];
    int n4[8];
};

__global__ __launch_bounds__(256) void cast_kernel(CastArgs a) {
    const int y = blockIdx.y;
    const int n4 = a.n4[y];
    if (y == 7) {
        // RoPE trig tables: dst[7] = cos table (fp32), sin table right after.
        const float* s = a.src[7];
        float* c  = (float*)a.dst[7];
        float* sn = c + 131072;
        for (int i = blockIdx.x * blockDim.x + threadIdx.x; i < n4; i += gridDim.x * blockDim.x) {
            f32x4 v = *(const f32x4*)&s[(size_t)i * 4];
            f32x4 cv, sv;
            #pragma unroll
            for (int j = 0; j < 4; j++) {
                float ss, cc;
                __sincosf(v[j], &ss, &cc);
                sv[j] = ss; cv[j] = cc;
            }
            *(f32x4*)&c[(size_t)i * 4]  = cv;
            *(f32x4*)&sn[(size_t)i * 4] = sv;
        }
        return;
    }
    const float* s = a.src[y];
    u16* d = a.dst[y];
    for (int i = blockIdx.x * blockDim.x + threadIdx.x; i < n4; i += gridDim.x * blockDim.x) {
        f32x4 v = *(const f32x4*)&s[(size_t)i * 4];
        u16x4 o = { f32_to_bf16(v[0]), f32_to_bf16(v[1]), f32_to_bf16(v[2]), f32_to_bf16(v[3]) };
        *(u16x4*)&d[(size_t)i * 4] = o;
    }
}

#define GK 1024
#define GN 1024
#define GM 4096

// ---------------------------------------------------------------------------
// QKV projection GEMM + RoPE. 128x128 tile, BK=32, grid (32 m, 8 n, 3 z).
// z=0 Q: normal [t][HD] bf16, scaled 0.125*log2(e)  (softmax runs in exp2
//        domain; the -16 bias is seeded into the attn QK accumulator).
// z=1 K: KT[h][kb][ks][kl][32]   (dk halves ks -> 64 B rows)
// z=2 V: VT[h][kb][ks][dv][32']  (key halves; kappa permutation in slot idx)
// LDS staging/read pair uses the XOR bank swizzle.
// RoPE trig: reads precomputed cos/sin tables (csT, csT+131072) when
// available -- removes 32 __sincosf per lane from the epilogue; falls back
// to in-line __sincosf when csT == nullptr (workspace too small).
// ---------------------------------------------------------------------------
__global__ __launch_bounds__(256) void gemm_rope(
    const u16* __restrict__ A0, const u16* __restrict__ A1, const u16* __restrict__ A2,
    const u16* __restrict__ W0, const u16* __restrict__ W1, const u16* __restrict__ W2,
    u16* __restrict__ C0, u16* __restrict__ C1, u16* __restrict__ C2,
    const float* __restrict__ freqs, const float* __restrict__ csT)
{
    __shared__ u16 SM[8192];
    u16* As = SM;
    u16* Bs = SM + 4096;

    const int z = blockIdx.z;
    const u16* A = (z == 0) ? A0 : ((z == 1) ? A1 : A2);
    const u16* W = (z == 0) ? W0 : ((z == 1) ? W1 : W2);
    u16* Cb      = (z == 0) ? C0 : ((z == 1) ? C1 : C2);
    const float ascale = (z == 0) ? 0.18033688f : 1.0f;   // 0.125 * log2(e)

    const int tid  = threadIdx.x;
    const int w    = tid >> 6;
    const int lane = tid & 63;
    const int quad = lane >> 4;
    const int l16  = lane & 15;
    const int m0 = blockIdx.x * 128;
    const int n0 = blockIdx.y * 128;
    const int wm = (w >> 1) * 64;
    const int wn = (w & 1) * 64;

    const int sr = tid >> 2;
    const int sc = (((tid & 3) ^ ((tid >> 3) & 3))) * 8;   // swizzled source chunk
    const size_t aoff0 = (size_t)(m0 + sr) * GK + sc;
    const size_t aoff1 = aoff0 + (size_t)64 * GK;
    const size_t boff0 = (size_t)(n0 + sr) * GK + sc;
    const size_t boff1 = boff0 + (size_t)64 * GK;
    u16* ldsA0 = &As[w * 512];
    u16* ldsA1 = &As[2048 + w * 512];
    u16* ldsB0 = &Bs[w * 512];
    u16* ldsB1 = &Bs[2048 + w * 512];

    const int csw = (quad ^ ((l16 >> 1) & 3)) * 8;          // swizzled read chunk

    f32x4 acc[4][4];
    for (int i = 0; i < 4; i++)
        for (int j = 0; j < 4; j++) acc[i][j] = 0.f;

    for (int k0 = 0; k0 < GK; k0 += 32) {
        gl_lds16(A + aoff0 + k0, ldsA0);
        gl_lds16(A + aoff1 + k0, ldsA1);
        gl_lds16(W + boff0 + k0, ldsB0);
        gl_lds16(W + boff1 + k0, ldsB1);
        __syncthreads();

        bf16x8 af[4], bfr[4];
        for (int t = 0; t < 4; t++) {
            af[t]  = *(const bf16x8*)&As[(wm + t * 16 + l16) * 32 + csw];
            bfr[t] = *(const bf16x8*)&Bs[(wn + t * 16 + l16) * 32 + csw];
        }
        for (int mt = 0; mt < 4; mt++)
            for (int nt = 0; nt < 4; nt++)
                acc[mt][nt] = __builtin_amdgcn_mfma_f32_16x16x32_bf16(
                    af[mt], bfr[nt], acc[mt][nt], 0, 0, 0);
        __syncthreads();
    }
    // after final barrier As/Bs are dead; per-wave scratch (wave-private)
    u16* tr = SM + w * 1152;  // 16 rows x 72 u16

    const int hh = (n0 + wn) >> 6;
    const size_t tb = (size_t)hh * 262144 + (size_t)((m0 + wm) >> 6) * 4096;
    const float* snT = csT ? (csT + 131072) : (const float*)0;

    if (z != 2) {
        for (int mt = 0; mt < 4; mt++) {
            #pragma unroll
            for (int r = 0; r < 4; r++) {
                int m = m0 + wm + mt * 16 + quad * 4 + r;
                float v0 = acc[mt][0][r];
                float v1 = acc[mt][1][r];
                float s0, c0, s1, c1;
                if (csT) {
                    c0 = csT[m * 32 + l16];      s0 = snT[m * 32 + l16];
                    c1 = csT[m * 32 + 16 + l16]; s1 = snT[m * 32 + 16 + l16];
                } else {
                    __sincosf(freqs[m * 32 + l16], &s0, &c0);
                    __sincosf(freqs[m * 32 + 16 + l16], &s1, &c1);
                }
                int row = quad * 4 + r;
                tr[row * 72 + l16]      = f32_to_bf16((v0 * c0 - v1 * s0) * ascale);
                tr[row * 72 + 16 + l16] = f32_to_bf16((v1 * c1 + v0 * s1) * ascale);
                tr[row * 72 + 32 + l16] = f32_to_bf16(acc[mt][2][r] * ascale);
                tr[row * 72 + 48 + l16] = f32_to_bf16(acc[mt][3][r] * ascale);
            }
            // wave-private transpose read: lane -> row l16, cols quad*16..+16
            u16x8 va = *(const u16x8*)&tr[l16 * 72 + quad * 16];
            u16x8 vb = *(const u16x8*)&tr[l16 * 72 + quad * 16 + 8];
            if (z == 0) {
                size_t base = (size_t)(m0 + wm + mt * 16 + l16) * GN + n0 + wn + quad * 16;
                *(u16x8*)&Cb[base]     = va;
                *(u16x8*)&Cb[base + 8] = vb;
            } else {
                // K half-split: dk = quad*16 + c -> half ks = quad>>1, within = (quad&1)*16 + c
                size_t base = tb + (size_t)(quad >> 1) * 2048
                            + (size_t)(mt * 16 + l16) * 32 + (quad & 1) * 16;
                *(u16x8*)&Cb[base]     = va;
                *(u16x8*)&Cb[base + 8] = vb;
            }
        }
    } else {
        // V: VT[h][kb][ks][dv][32'], kappa within each 32-key half
        for (int mt = 0; mt < 4; mt++) {
            float o0[4], o1[4];
            for (int r = 0; r < 4; r++) {
                int m = m0 + wm + mt * 16 + quad * 4 + r;
                float v0 = acc[mt][0][r];
                float v1 = acc[mt][1][r];
                float s0, c0, s1, c1;
                if (csT) {
                    c0 = csT[m * 32 + l16];      s0 = snT[m * 32 + l16];
                    c1 = csT[m * 32 + 16 + l16]; s1 = snT[m * 32 + 16 + l16];
                } else {
                    __sincosf(freqs[m * 32 + l16], &s0, &c0);
                    __sincosf(freqs[m * 32 + 16 + l16], &s1, &c1);
                }
                o0[r] = v0 * c0 - v1 * s0;
                o1[r] = v1 * c1 + v0 * s1;
            }
            const int ks = mt >> 1;                       // key half
            const int sl = 4 * (mt & 1) + 8 * quad;       // slot within half (r adds 0..3)
            const size_t hb = tb + (size_t)ks * 2048 + sl;
            u16x4 u;
            u = { f32_to_bf16(o0[0]), f32_to_bf16(o0[1]), f32_to_bf16(o0[2]), f32_to_bf16(o0[3]) };
            *(u16x4*)&Cb[hb + (size_t)l16 * 32] = u;
            u = { f32_to_bf16(o1[0]), f32_to_bf16(o1[1]), f32_to_bf16(o1[2]), f32_to_bf16(o1[3]) };
            *(u16x4*)&Cb[hb + (size_t)(16 + l16) * 32] = u;
            u = { f32_to_bf16(acc[mt][2][0]), f32_to_bf16(acc[mt][2][1]),
                  f32_to_bf16(acc[mt][2][2]), f32_to_bf16(acc[mt][2][3]) };
            *(u16x4*)&Cb[hb + (size_t)(32 + l16) * 32] = u;
            u = { f32_to_bf16(acc[mt][3][0]), f32_to_bf16(acc[mt][3][1]),
                  f32_to_bf16(acc[mt][3][2]), f32_to_bf16(acc[mt][3][3]) };
            *(u16x4*)&Cb[hb + (size_t)(48 + l16) * 32] = u;
        }
    }
}

// ---------------------------------------------------------------------------
// Output projection GEMM. Tile 64x128, grid (64 m, 8 n) = 512 blocks = 2/CU.
// Full K=1024, fp32 stores direct to d_out. XOR bank swizzle on staging/reads.
// ---------------------------------------------------------------------------
__global__ __launch_bounds__(256) void gemm_out(
    const u16* __restrict__ A, const u16* __restrict__ W, float* __restrict__ C)
{
    __shared__ u16 SM[8704];   // staging 6144 u16 (A 2048 | B 4096); tr 17408 B
    u16* As = SM;              // 64 x 32
    u16* Bs = SM + 2048;       // 128 x 32

    const int tid  = threadIdx.x;
    const int w    = tid >> 6;
    const int lane = tid & 63;
    const int quad = lane >> 4;
    const int l16  = lane & 15;
    const int m0 = blockIdx.x * 64;
    const int n0 = blockIdx.y * 128;
    const int wm = (w >> 1) * 32;
    const int wn = (w & 1) * 64;

    const int sr = tid >> 2;
    const int sc = (((tid & 3) ^ ((tid >> 3) & 3))) * 8;   // swizzled source chunk
    const size_t aoff  = (size_t)(m0 + sr) * GK + sc;
    const size_t boff0 = (size_t)(n0 + sr) * GK + sc;
    const size_t boff1 = boff0 + (size_t)64 * GK;
    u16* ldsA  = &As[w * 512];
    u16* ldsB0 = &Bs[w * 512];
    u16* ldsB1 = &Bs[2048 + w * 512];

    const int csw = (quad ^ ((l16 >> 1) & 3)) * 8;

    f32x4 acc[2][4];
    for (int i = 0; i < 2; i++)
        for (int j = 0; j < 4; j++) acc[i][j] = 0.f;

    for (int k0 = 0; k0 < GK; k0 += 32) {
        gl_lds16(A + aoff + k0, ldsA);
        gl_lds16(W + boff0 + k0, ldsB0);
        gl_lds16(W + boff1 + k0, ldsB1);
        __syncthreads();

        bf16x8 af[2], bfr[4];
        for (int t = 0; t < 2; t++)
            af[t] = *(const bf16x8*)&As[(wm + t * 16 + l16) * 32 + csw];
        for (int t = 0; t < 4; t++)
            bfr[t] = *(const bf16x8*)&Bs[(wn + t * 16 + l16) * 32 + csw];
        for (int mt = 0; mt < 2; mt++)
            for (int nt = 0; nt < 4; nt++)
                acc[mt][nt] = __builtin_amdgcn_mfma_f32_16x16x32_bf16(
                    af[mt], bfr[nt], acc[mt][nt], 0, 0, 0);
        __syncthreads();
    }

    // per-wave fp32 transpose scratch: 16 rows x 68 floats
    float* tr = (float*)SM + w * 1088;
    for (int mt = 0; mt < 2; mt++) {
        #pragma unroll
        for (int nt = 0; nt < 4; nt++)
            #pragma unroll
            for (int r = 0; r < 4; r++)
                tr[(quad * 4 + r) * 68 + nt * 16 + l16] = acc[mt][nt][r];
        size_t base = (size_t)(m0 + wm + mt * 16 + l16) * GN + n0 + wn + quad * 16;
        #pragma unroll
        for (int c = 0; c < 4; c++) {
            f32x4 v = *(const f32x4*)&tr[l16 * 68 + quad * 16 + c * 4];
            *(f32x4*)&C[base + c * 4] = v;
        }
    }
}

// ---------------------------------------------------------------------------
// Flash attention, causal. One block per (head, 64-row q-block): grid 1024,
// long blocks (qb large) dispatched FIRST (qb = 63 - (id>>4)) so the
// hardware scheduler backfills short ones -> dynamic load balance.
// LDS 50176 B (KV dbuf 32768 + dedicated EX 17408) -> 3 blocks/CU
// (__launch_bounds__(256,3)). NOTE: every 4-blocks/CU variant of this
// kernel (rounds 7/8/9: KV-overlay, register-only epilogue, 32KB LDS)
// failed nondeterministically; 3-resident with dedicated EX is the proven
// safe configuration — do not retry 4-resident without new evidence.
// Per-iteration body: 2-D wave split (wave owns 32q x 32k), exp2-domain
// softmax (Q pre-scaled by 0.125*log2e, -16*log2e seeded in the QK
// accumulator), denominator via ones-MFMA, K/V double-buffered via
// global_load_lds, one barrier/iter.
// XCD locality: h = (id&7)*2 + ((id>>3)&1) keeps 2 heads (2MB KV) per XCD L2.
// ---------------------------------------------------------------------------
__global__ __launch_bounds__(256, 3) void attn_kernel(
    const u16* __restrict__ Qb, const u16* __restrict__ KT,
    const u16* __restrict__ VTg, u16* __restrict__ valsb)
{
    __shared__ __align__(16) u16 KV[2][8192];   // [buf][ K 4096 | V 4096 ] u16
    __shared__ __align__(16) float EX[4352];    // exchange / transpose scratch

    const int tid  = threadIdx.x;
    const int w    = tid >> 6;
    const int lane = tid & 63;
    const int quad = lane >> 4;
    const int l16  = lane & 15;
    const int HD = 1024;

    const int id = blockIdx.x;
    const int h  = (id & 7) * 2 + ((id >> 3) & 1);   // 2 heads per XCD -> L2-local KV
    const int qb = 63 - (id >> 4);                   // long blocks first

    const u16* kt = KT  + (size_t)h * 262144;
    const u16* vt = VTg + (size_t)h * 262144;

    const int wq = w >> 1;     // q half owned (32 rows)
    const int wk = w & 1;      // key half owned (32 keys)

    // swizzled per-lane DMA source offset within a 1KB (16-row) span
    const int dmaoff = (lane >> 2) * 32 + ((lane & 3) ^ ((lane >> 3) & 3)) * 8;
    const int csw = (quad ^ ((l16 >> 1) & 3)) * 8;   // swizzled read chunk

    // ones A-fragment for the denominator MFMA
    bf16x8 ones;
    #pragma unroll
    for (int i = 0; i < 8; i++) ones[i] = (short)0x3F80;   // bf16 1.0
    const f32x4 seed = { -23.0831204f, -23.0831204f, -23.0831204f, -23.0831204f };

    // Q B-frags for this wave's 32 q rows (2 groups x 2 dk halves)
    bf16x8 bq[2][2];
    #pragma unroll
    for (int qt = 0; qt < 2; qt++) {
        const size_t qrow = (size_t)(qb * 64 + wq * 32 + qt * 16 + l16);
        bq[qt][0] = *(const bf16x8*)&Qb[qrow * HD + h * 64 + quad * 8];
        bq[qt][1] = *(const bf16x8*)&Qb[qrow * HD + h * 64 + 32 + quad * 8];
    }

    f32x4 o[2][4];
    #pragma unroll
    for (int i = 0; i < 2; i++)
        #pragma unroll
        for (int j = 0; j < 4; j++) o[i][j] = 0.f;
    f32x4 ls_acc[2];
    ls_acc[0] = 0.f;
    ls_acc[1] = 0.f;

    // prologue DMA: tile 0 -> buf 0
    #pragma unroll
    for (int i = 0; i < 2; i++) {
        gl_lds16(kt + i * 2048 + w * 512 + dmaoff, &KV[0][i * 2048 + w * 512]);
        gl_lds16(vt + i * 2048 + w * 512 + dmaoff, &KV[0][4096 + i * 2048 + w * 512]);
    }

    for (int kb = 0; kb <= qb; kb++) {
        __syncthreads();  // DMA for kb drained; buf[(kb+1)&1] free
        if (kb < qb) {
            const int nb = (kb + 1) & 1;
            const u16* ksrc = kt + (size_t)(kb + 1) * 4096;
            const u16* vsrc = vt + (size_t)(kb + 1) * 4096;
            #pragma unroll
            for (int i = 0; i < 2; i++) {
                gl_lds16(ksrc + i * 2048 + w * 512 + dmaoff, &KV[nb][i * 2048 + w * 512]);
                gl_lds16(vsrc + i * 2048 + w * 512 + dmaoff, &KV[nb][4096 + i * 2048 + w * 512]);
            }
        }
        const u16* Ksb = &KV[kb & 1][0];
        const u16* Vsb = &KV[kb & 1][4096];

        // K frags: only this wave's 32-key half (both dk halves)
        bf16x8 ak[2][2];
        #pragma unroll
        for (int kt2 = 0; kt2 < 2; kt2++) {
            const int krow = wk * 32 + kt2 * 16 + l16;
            ak[kt2][0] = *(const bf16x8*)&Ksb[krow * 32 + csw];
            ak[kt2][1] = *(const bf16x8*)&Ksb[2048 + krow * 32 + csw];
        }

        // S^T = K * Q^T (exp2 domain, bias seeded into accumulator)
        f32x4 s[2][2];
        #pragma unroll
        for (int qt = 0; qt < 2; qt++)
            #pragma unroll
            for (int kt2 = 0; kt2 < 2; kt2++) {
                f32x4 z4 = seed;
                z4 = __builtin_amdgcn_mfma_f32_16x16x32_bf16(ak[kt2][0], bq[qt][0], z4, 0, 0, 0);
                s[qt][kt2] = __builtin_amdgcn_mfma_f32_16x16x32_bf16(ak[kt2][1], bq[qt][1], z4, 0, 0, 0);
            }

        if (kb == qb) {  // diagonal: mask key > q
            #pragma unroll
            for (int qt = 0; qt < 2; qt++)
                #pragma unroll
                for (int kt2 = 0; kt2 < 2; kt2++)
                    #pragma unroll
                    for (int r = 0; r < 4; r++)
                        if (wk * 32 + kt2 * 16 + quad * 4 + r > wq * 32 + qt * 16 + l16)
                            s[qt][kt2][r] = -1e30f;
        }

        // V frags (this wave's key half) issued before exp so lgkmcnt hides
        bf16x8 av[4];
        #pragma unroll
        for (int nv = 0; nv < 4; nv++)
            av[nv] = *(const bf16x8*)&Vsb[wk * 2048 + (nv * 16 + l16) * 32 + csw];

        // p = exp2(s): one v_exp_f32 per element, no prologue VALU
        #pragma unroll
        for (int qt = 0; qt < 2; qt++)
            #pragma unroll
            for (int kt2 = 0; kt2 < 2; kt2++)
                #pragma unroll
                for (int r = 0; r < 4; r++)
                    s[qt][kt2][r] = EXP2(s[qt][kt2][r]);

        bf16x8 bp[2];
        #pragma unroll
        for (int qt = 0; qt < 2; qt++) {
            bf16x8 b = { f32_to_bf16_trunc(s[qt][0][0]), f32_to_bf16_trunc(s[qt][0][1]),
                         f32_to_bf16_trunc(s[qt][0][2]), f32_to_bf16_trunc(s[qt][0][3]),
                         f32_to_bf16_trunc(s[qt][1][0]), f32_to_bf16_trunc(s[qt][1][1]),
                         f32_to_bf16_trunc(s[qt][1][2]), f32_to_bf16_trunc(s[qt][1][3]) };
            bp[qt] = b;
        }

        // denominator via matrix pipe: ls_acc[qt] += ones x P
        #pragma unroll
        for (int qt = 0; qt < 2; qt++)
            ls_acc[qt] = __builtin_amdgcn_mfma_f32_16x16x32_bf16(
                ones, bp[qt], ls_acc[qt], 0, 0, 0);

        // 8 independent accumulator chains
        #pragma unroll
        for (int nv = 0; nv < 4; nv++)
            #pragma unroll
            for (int qt = 0; qt < 2; qt++)
                o[qt][nv] = __builtin_amdgcn_mfma_f32_16x16x32_bf16(
                    av[nv], bp[qt], o[qt][nv], 0, 0, 0);
    }

    // ---- epilogue: combine key-half partials across the wave pair ----
    // ls_acc rows are all identical (ones x P) -> per-lane denominator
    // for q row l16 of group qt is ls_acc[qt][0]; no shfl needed.
    const float lsum0 = ls_acc[0][0];
    const float lsum1 = ls_acc[1][0];

    // wave keeps q-group wk, sends q-group wk^1 to partner wave (w^1).
    // All register indices static (wave-uniform branch on wk).
    float* my = EX + (w * 64 + lane) * 17;
    if (wk == 0) {
        #pragma unroll
        for (int nv = 0; nv < 4; nv++) *(f32x4*)&my[nv * 4] = o[1][nv];
        my[16] = lsum1;
    } else {
        #pragma unroll
        for (int nv = 0; nv < 4; nv++) *(f32x4*)&my[nv * 4] = o[0][nv];
        my[16] = lsum0;
    }
    __syncthreads();   // exchange visible
    const float* pr = EX + ((w ^ 1) * 64 + lane) * 17;
    f32x4 fin[4];
    float denom;
    if (wk == 0) {
        #pragma unroll
        for (int nv = 0; nv < 4; nv++) fin[nv] = o[0][nv] + *(const f32x4*)&pr[nv * 4];
        denom = lsum0 + pr[16];
    } else {
        #pragma unroll
        for (int nv = 0; nv < 4; nv++) fin[nv] = o[1][nv] + *(const f32x4*)&pr[nv * 4];
        denom = lsum1 + pr[16];
    }
    const float inv = 1.f / denom;
    __syncthreads();   // exchange reads done; EX reusable as scratch

    // wave-private transpose scratch: 16 rows x 68 floats
    float* myOw = EX + w * 1088;
    #pragma unroll
    for (int nv = 0; nv < 4; nv++)
        #pragma unroll
        for (int r = 0; r < 4; r++)
            myOw[l16 * 68 + nv * 16 + quad * 4 + r] = fin[nv][r] * inv;
    #pragma unroll
    for (int i = 0; i < 4; i++) {
        int row = i * 4 + quad;   // q row within this wave's owned 16
        f32x4 vv = *(const f32x4*)&myOw[row * 68 + l16 * 4];
        u16x4 u = { f32_to_bf16(vv[0]), f32_to_bf16(vv[1]), f32_to_bf16(vv[2]), f32_to_bf16(vv[3]) };
        *(u16x4*)&valsb[(size_t)(qb * 64 + wq * 32 + wk * 16 + row) * HD + h * 64 + l16 * 4] = u;
    }
}

// ---------------------------------------------------------------------------
// ws layout (u16 idx): qc 0 | kc 4M | vc 8M | wqc 12M | wkc 13M | wvc 14M |
// woc 15M | Qb 16M | KT 20M | VT 24M | trig tables 28M (if ws allows).
// valsb reuses qc. Base 56 MiB + 1 MiB tables.
// ---------------------------------------------------------------------------
extern "C" void kernel_launch(void* const* d_in, const int* in_sizes, int n_in,
                              void* d_out, int out_size, void* d_ws, size_t ws_size,
                              hipStream_t stream) {
    const float* q     = (const float*)d_in[0];
    const float* k     = (const float*)d_in[1];
    const float* v     = (const float*)d_in[2];
    const float* freqs = (const float*)d_in[4];
    const float* wq    = (const float*)d_in[5];
    const float* wk    = (const float*)d_in[6];
    const float* wv    = (const float*)d_in[7];
    const float* wo    = (const float*)d_in[8];

    u16* B = (u16*)d_ws;
    u16* qc  = B;
    u16* kc  = B + (size_t)4194304;
    u16* vc  = B + (size_t)8388608;
    u16* wqc = B + (size_t)12582912;
    u16* wkc = B + (size_t)13631488;
    u16* wvc = B + (size_t)14680064;
    u16* woc = B + (size_t)15728640;
    u16* Qb  = B + (size_t)16777216;
    u16* KT  = B + (size_t)20971520;
    u16* VT  = B + (size_t)25165824;
    u16* valsb = qc;   // qc dead after gemm_rope reads it

    // trig tables after VT: cos [131072 floats] then sin [131072 floats]
    const size_t tab_off_u16 = 29360128;                 // byte 58720256
    const size_t need_bytes  = 58720256 + 2 * 131072 * sizeof(float);
    float* csT = (ws_size >= need_bytes) ? (float*)(B + tab_off_u16) : (float*)0;

    CastArgs ca;
    ca.src[0] = q;  ca.dst[0] = qc;  ca.n4[0] = 1048576;
    ca.src[1] = k;  ca.dst[1] = kc;  ca.n4[1] = 1048576;
    ca.src[2] = v;  ca.dst[2] = vc;  ca.n4[2] = 1048576;
    ca.src[3] = wq; ca.dst[3] = wqc; ca.n4[3] = 262144;
    ca.src[4] = wk; ca.dst[4] = wkc; ca.n4[4] = 262144;
    ca.src[5] = wv; ca.dst[5] = wvc; ca.n4[5] = 262144;
    ca.src[6] = wo; ca.dst[6] = woc; ca.n4[6] = 262144;
    ca.src[7] = freqs; ca.dst[7] = (u16*)csT; ca.n4[7] = csT ? 32768 : 0;
    cast_kernel<<<dim3(1024, 8), 256, 0, stream>>>(ca);

    gemm_rope<<<dim3(32, 8, 3), 256, 0, stream>>>(
        qc, kc, vc, wqc, wkc, wvc, Qb, KT, VT, freqs, csT);

    attn_kernel<<<dim3(1024), 256, 0, stream>>>(Qb, KT, VT, valsb);

    gemm_out<<<dim3(64, 8), 256, 0, stream>>>(valsb, woc, (float*)d_out);
}

// Round 12
// 260.485 us; speedup vs baseline: 1.0411x; 1.0411x over previous
//
#include <hip/hip_runtime.h>

typedef unsigned short u16;
typedef unsigned int u32;
typedef short bf16x8 __attribute__((ext_vector_type(8)));
typedef float f32x4 __attribute__((ext_vector_type(4)));
typedef unsigned short u16x4 __attribute__((ext_vector_type(4)));
typedef unsigned short u16x8 __attribute__((ext_vector_type(8)));

__device__ __forceinline__ u16 f32_to_bf16(float f) {
    u32 u = __float_as_uint(f);
    u += 0x7FFFu + ((u >> 16) & 1u);
    return (u16)(u >> 16);
}
// truncating cast (p in [0,1], P-matrix only)
__device__ __forceinline__ short f32_to_bf16_trunc(float f) {
    return (short)(__float_as_uint(f) >> 16);
}

// native exp2 (v_exp_f32); fallback via __expf if builtin missing
#if __has_builtin(__builtin_amdgcn_exp2f)
#define EXP2(x) __builtin_amdgcn_exp2f(x)
#else
#define EXP2(x) __expf((x) * 0.69314718056f)
#endif

// async global->LDS, 16B per lane; lds pointer must be wave-uniform
__device__ __forceinline__ void gl_lds16(const u16* g, u16* l) {
    __builtin_amdgcn_global_load_lds(
        (const __attribute__((address_space(1))) u32*)g,
        (__attribute__((address_space(3))) u32*)l, 16, 0, 0);
}

// Bank-conflict swizzle for 64B-row LDS tiles read as (row*32 + chunk*8) u16:
// physical chunk = logical chunk ^ ((row>>1)&3). Folded into the DMA *source*
// address (per-lane), so LDS writes stay contiguous. Makes each 8-lane phase
// of a ds_read_b128 hit all 8 bank groups (was 4-way conflicted).

// ---------------------------------------------------------------------------
// bulk fp32 -> bf16 cast; slice y==7 builds the RoPE cos/sin tables
// (same __sincosf as the previous in-line epilogue -> bit-identical values).
// ---------------------------------------------------------------------------
struct CastArgs {
    const float* src[8];
    u16* dst[8];
    int n4[8];
};

__global__ __launch_bounds__(256) void cast_kernel(CastArgs a) {
    const int y = blockIdx.y;
    const int n4 = a.n4[y];
    if (y == 7) {
        // RoPE trig tables: dst[7] = cos table (fp32), sin table right after.
        const float* s = a.src[7];
        float* c  = (float*)a.dst[7];
        float* sn = c + 131072;
        for (int i = blockIdx.x * blockDim.x + threadIdx.x; i < n4; i += gridDim.x * blockDim.x) {
            f32x4 v = *(const f32x4*)&s[(size_t)i * 4];
            f32x4 cv, sv;
            #pragma unroll
            for (int j = 0; j < 4; j++) {
                float ss, cc;
                __sincosf(v[j], &ss, &cc);
                sv[j] = ss; cv[j] = cc;
            }
            *(f32x4*)&c[(size_t)i * 4]  = cv;
            *(f32x4*)&sn[(size_t)i * 4] = sv;
        }
        return;
    }
    const float* s = a.src[y];
    u16* d = a.dst[y];
    for (int i = blockIdx.x * blockDim.x + threadIdx.x; i < n4; i += gridDim.x * blockDim.x) {
        f32x4 v = *(const f32x4*)&s[(size_t)i * 4];
        u16x4 o = { f32_to_bf16(v[0]), f32_to_bf16(v[1]), f32_to_bf16(v[2]), f32_to_bf16(v[3]) };
        *(u16x4*)&d[(size_t)i * 4] = o;
    }
}

#define GK 1024
#define GN 1024
#define GM 4096

// ---------------------------------------------------------------------------
// QKV projection GEMM + RoPE. 128x128 tile, BK=32, grid (32 m, 8 n, 3 z).
// MAIN LOOP now uses the attn-proven single-barrier DOUBLE-BUFFER protocol:
// prologue-stage tile 0; each iter: barrier (drains DMA issued one full
// compute body earlier -> latency hidden), issue DMA for tile k+1 into
// buf^1, compute tile k from buf k. One barrier/iter instead of two, and
// the vmcnt(0) drain no longer exposes DMA latency (round-11 profile:
// MfmaUtil 17%, VALU 12%, HBM 14% -> staging-latency-bound).
// z=0 Q: normal [t][HD] bf16, scaled 0.125*log2(e).
// z=1 K: KT[h][kb][ks][kl][32]; z=2 V: VT[h][kb][ks][dv][32'].
// RoPE trig from precomputed tables (csT) with in-line fallback.
// ---------------------------------------------------------------------------
__global__ __launch_bounds__(256) void gemm_rope(
    const u16* __restrict__ A0, const u16* __restrict__ A1, const u16* __restrict__ A2,
    const u16* __restrict__ W0, const u16* __restrict__ W1, const u16* __restrict__ W2,
    u16* __restrict__ C0, u16* __restrict__ C1, u16* __restrict__ C2,
    const float* __restrict__ freqs, const float* __restrict__ csT)
{
    __shared__ u16 SM[16384];   // [buf][ A 4096 | B 4096 ] u16, double-buffered

    const int z = blockIdx.z;
    const u16* A = (z == 0) ? A0 : ((z == 1) ? A1 : A2);
    const u16* W = (z == 0) ? W0 : ((z == 1) ? W1 : W2);
    u16* Cb      = (z == 0) ? C0 : ((z == 1) ? C1 : C2);
    const float ascale = (z == 0) ? 0.18033688f : 1.0f;   // 0.125 * log2(e)

    const int tid  = threadIdx.x;
    const int w    = tid >> 6;
    const int lane = tid & 63;
    const int quad = lane >> 4;
    const int l16  = lane & 15;
    const int m0 = blockIdx.x * 128;
    const int n0 = blockIdx.y * 128;
    const int wm = (w >> 1) * 64;
    const int wn = (w & 1) * 64;

    const int sr = tid >> 2;
    const int sc = (((tid & 3) ^ ((tid >> 3) & 3))) * 8;   // swizzled source chunk
    const size_t aoff0 = (size_t)(m0 + sr) * GK + sc;
    const size_t aoff1 = aoff0 + (size_t)64 * GK;
    const size_t boff0 = (size_t)(n0 + sr) * GK + sc;
    const size_t boff1 = boff0 + (size_t)64 * GK;

    const int csw = (quad ^ ((l16 >> 1) & 3)) * 8;          // swizzled read chunk

    f32x4 acc[4][4];
    for (int i = 0; i < 4; i++)
        for (int j = 0; j < 4; j++) acc[i][j] = 0.f;

    // prologue: stage tile 0 -> buf 0
    {
        u16* Ab = SM;
        gl_lds16(A + aoff0, &Ab[w * 512]);
        gl_lds16(A + aoff1, &Ab[2048 + w * 512]);
        gl_lds16(W + boff0, &Ab[4096 + w * 512]);
        gl_lds16(W + boff1, &Ab[4096 + 2048 + w * 512]);
    }

    for (int it = 0; it < 32; ++it) {
        __syncthreads();   // DMA for tile it drained; buf^1 free for prefetch
        if (it < 31) {
            const int k0 = (it + 1) * 32;
            u16* Ab = SM + ((it + 1) & 1) * 8192;
            gl_lds16(A + aoff0 + k0, &Ab[w * 512]);
            gl_lds16(A + aoff1 + k0, &Ab[2048 + w * 512]);
            gl_lds16(W + boff0 + k0, &Ab[4096 + w * 512]);
            gl_lds16(W + boff1 + k0, &Ab[4096 + 2048 + w * 512]);
        }
        const u16* As = SM + (it & 1) * 8192;
        const u16* Bs = As + 4096;

        bf16x8 af[4], bfr[4];
        for (int t = 0; t < 4; t++) {
            af[t]  = *(const bf16x8*)&As[(wm + t * 16 + l16) * 32 + csw];
            bfr[t] = *(const bf16x8*)&Bs[(wn + t * 16 + l16) * 32 + csw];
        }
        for (int mt = 0; mt < 4; mt++)
            for (int nt = 0; nt < 4; nt++)
                acc[mt][nt] = __builtin_amdgcn_mfma_f32_16x16x32_bf16(
                    af[mt], bfr[nt], acc[mt][nt], 0, 0, 0);
    }
    __syncthreads();   // all compute done; SM dead -> reusable as scratch
    // per-wave scratch (wave-private)
    u16* tr = SM + w * 1152;  // 16 rows x 72 u16

    const int hh = (n0 + wn) >> 6;
    const size_t tb = (size_t)hh * 262144 + (size_t)((m0 + wm) >> 6) * 4096;
    const float* snT = csT ? (csT + 131072) : (const float*)0;

    if (z != 2) {
        for (int mt = 0; mt < 4; mt++) {
            #pragma unroll
            for (int r = 0; r < 4; r++) {
                int m = m0 + wm + mt * 16 + quad * 4 + r;
                float v0 = acc[mt][0][r];
                float v1 = acc[mt][1][r];
                float s0, c0, s1, c1;
                if (csT) {
                    c0 = csT[m * 32 + l16];      s0 = snT[m * 32 + l16];
                    c1 = csT[m * 32 + 16 + l16]; s1 = snT[m * 32 + 16 + l16];
                } else {
                    __sincosf(freqs[m * 32 + l16], &s0, &c0);
                    __sincosf(freqs[m * 32 + 16 + l16], &s1, &c1);
                }
                int row = quad * 4 + r;
                tr[row * 72 + l16]      = f32_to_bf16((v0 * c0 - v1 * s0) * ascale);
                tr[row * 72 + 16 + l16] = f32_to_bf16((v1 * c1 + v0 * s1) * ascale);
                tr[row * 72 + 32 + l16] = f32_to_bf16(acc[mt][2][r] * ascale);
                tr[row * 72 + 48 + l16] = f32_to_bf16(acc[mt][3][r] * ascale);
            }
            // wave-private transpose read: lane -> row l16, cols quad*16..+16
            u16x8 va = *(const u16x8*)&tr[l16 * 72 + quad * 16];
            u16x8 vb = *(const u16x8*)&tr[l16 * 72 + quad * 16 + 8];
            if (z == 0) {
                size_t base = (size_t)(m0 + wm + mt * 16 + l16) * GN + n0 + wn + quad * 16;
                *(u16x8*)&Cb[base]     = va;
                *(u16x8*)&Cb[base + 8] = vb;
            } else {
                // K half-split: dk = quad*16 + c -> half ks = quad>>1, within = (quad&1)*16 + c
                size_t base = tb + (size_t)(quad >> 1) * 2048
                            + (size_t)(mt * 16 + l16) * 32 + (quad & 1) * 16;
                *(u16x8*)&Cb[base]     = va;
                *(u16x8*)&Cb[base + 8] = vb;
            }
        }
    } else {
        // V: VT[h][kb][ks][dv][32'], kappa within each 32-key half
        for (int mt = 0; mt < 4; mt++) {
            float o0[4], o1[4];
            for (int r = 0; r < 4; r++) {
                int m = m0 + wm + mt * 16 + quad * 4 + r;
                float v0 = acc[mt][0][r];
                float v1 = acc[mt][1][r];
                float s0, c0, s1, c1;
                if (csT) {
                    c0 = csT[m * 32 + l16];      s0 = snT[m * 32 + l16];
                    c1 = csT[m * 32 + 16 + l16]; s1 = snT[m * 32 + 16 + l16];
                } else {
                    __sincosf(freqs[m * 32 + l16], &s0, &c0);
                    __sincosf(freqs[m * 32 + 16 + l16], &s1, &c1);
                }
                o0[r] = v0 * c0 - v1 * s0;
                o1[r] = v1 * c1 + v0 * s1;
            }
            const int ks = mt >> 1;                       // key half
            const int sl = 4 * (mt & 1) + 8 * quad;       // slot within half (r adds 0..3)
            const size_t hb = tb + (size_t)ks * 2048 + sl;
            u16x4 u;
            u = { f32_to_bf16(o0[0]), f32_to_bf16(o0[1]), f32_to_bf16(o0[2]), f32_to_bf16(o0[3]) };
            *(u16x4*)&Cb[hb + (size_t)l16 * 32] = u;
            u = { f32_to_bf16(o1[0]), f32_to_bf16(o1[1]), f32_to_bf16(o1[2]), f32_to_bf16(o1[3]) };
            *(u16x4*)&Cb[hb + (size_t)(16 + l16) * 32] = u;
            u = { f32_to_bf16(acc[mt][2][0]), f32_to_bf16(acc[mt][2][1]),
                  f32_to_bf16(acc[mt][2][2]), f32_to_bf16(acc[mt][2][3]) };
            *(u16x4*)&Cb[hb + (size_t)(32 + l16) * 32] = u;
            u = { f32_to_bf16(acc[mt][3][0]), f32_to_bf16(acc[mt][3][1]),
                  f32_to_bf16(acc[mt][3][2]), f32_to_bf16(acc[mt][3][3]) };
            *(u16x4*)&Cb[hb + (size_t)(48 + l16) * 32] = u;
        }
    }
}

// ---------------------------------------------------------------------------
// Output projection GEMM. Tile 64x128, grid (64 m, 8 n) = 512 blocks = 2/CU.
// Same single-barrier double-buffer protocol as gemm_rope. fp32 stores
// direct to d_out. XOR bank swizzle on staging/reads.
// ---------------------------------------------------------------------------
__global__ __launch_bounds__(256) void gemm_out(
    const u16* __restrict__ A, const u16* __restrict__ W, float* __restrict__ C)
{
    __shared__ u16 SM[12288];  // [buf][ A 2048 | B 4096 ] u16, double-buffered

    const int tid  = threadIdx.x;
    const int w    = tid >> 6;
    const int lane = tid & 63;
    const int quad = lane >> 4;
    const int l16  = lane & 15;
    const int m0 = blockIdx.x * 64;
    const int n0 = blockIdx.y * 128;
    const int wm = (w >> 1) * 32;
    const int wn = (w & 1) * 64;

    const int sr = tid >> 2;
    const int sc = (((tid & 3) ^ ((tid >> 3) & 3))) * 8;   // swizzled source chunk
    const size_t aoff  = (size_t)(m0 + sr) * GK + sc;
    const size_t boff0 = (size_t)(n0 + sr) * GK + sc;
    const size_t boff1 = boff0 + (size_t)64 * GK;

    const int csw = (quad ^ ((l16 >> 1) & 3)) * 8;

    f32x4 acc[2][4];
    for (int i = 0; i < 2; i++)
        for (int j = 0; j < 4; j++) acc[i][j] = 0.f;

    // A staged by waves 0..3 over rows sr=tid>>2 (64 rows): A region 2048 u16.
    // prologue: stage tile 0 -> buf 0
    {
        u16* Ab = SM;
        gl_lds16(A + aoff,  &Ab[w * 512]);
        gl_lds16(W + boff0, &Ab[2048 + w * 512]);
        gl_lds16(W + boff1, &Ab[2048 + 2048 + w * 512]);
    }

    for (int it = 0; it < 32; ++it) {
        __syncthreads();   // DMA for tile it drained; buf^1 free
        if (it < 31) {
            const int k0 = (it + 1) * 32;
            u16* Ab = SM + ((it + 1) & 1) * 6144;
            gl_lds16(A + aoff + k0,  &Ab[w * 512]);
            gl_lds16(W + boff0 + k0, &Ab[2048 + w * 512]);
            gl_lds16(W + boff1 + k0, &Ab[2048 + 2048 + w * 512]);
        }
        const u16* As = SM + (it & 1) * 6144;
        const u16* Bs = As + 2048;

        bf16x8 af[2], bfr[4];
        for (int t = 0; t < 2; t++)
            af[t] = *(const bf16x8*)&As[(wm + t * 16 + l16) * 32 + csw];
        for (int t = 0; t < 4; t++)
            bfr[t] = *(const bf16x8*)&Bs[(wn + t * 16 + l16) * 32 + csw];
        for (int mt = 0; mt < 2; mt++)
            for (int nt = 0; nt < 4; nt++)
                acc[mt][nt] = __builtin_amdgcn_mfma_f32_16x16x32_bf16(
                    af[mt], bfr[nt], acc[mt][nt], 0, 0, 0);
    }
    __syncthreads();   // all compute done; SM dead -> reusable as scratch

    // per-wave fp32 transpose scratch: 16 rows x 68 floats
    float* tr = (float*)SM + w * 1088;
    for (int mt = 0; mt < 2; mt++) {
        #pragma unroll
        for (int nt = 0; nt < 4; nt++)
            #pragma unroll
            for (int r = 0; r < 4; r++)
                tr[(quad * 4 + r) * 68 + nt * 16 + l16] = acc[mt][nt][r];
        size_t base = (size_t)(m0 + wm + mt * 16 + l16) * GN + n0 + wn + quad * 16;
        #pragma unroll
        for (int c = 0; c < 4; c++) {
            f32x4 v = *(const f32x4*)&tr[l16 * 68 + quad * 16 + c * 4];
            *(f32x4*)&C[base + c * 4] = v;
        }
    }
}

// ---------------------------------------------------------------------------
// Flash attention, causal. One block per (head, 64-row q-block): grid 1024,
// long blocks (qb large) dispatched FIRST (qb = 63 - (id>>4)) so the
// hardware scheduler backfills short ones -> dynamic load balance.
// LDS 50176 B (KV dbuf 32768 + dedicated EX 17408) -> 3 blocks/CU
// (__launch_bounds__(256,3)). NOTE: every 4-blocks/CU variant of this
// kernel (rounds 7/8/9: KV-overlay, register-only epilogue, 32KB LDS)
// failed nondeterministically; 3-resident with dedicated EX is the proven
// safe configuration — do not retry 4-resident without new evidence.
// Per-iteration body: 2-D wave split (wave owns 32q x 32k), exp2-domain
// softmax (Q pre-scaled by 0.125*log2e, -16*log2e seeded in the QK
// accumulator), denominator via ones-MFMA, K/V double-buffered via
// global_load_lds, one barrier/iter.
// XCD locality: h = (id&7)*2 + ((id>>3)&1) keeps 2 heads (2MB KV) per XCD L2.
// ---------------------------------------------------------------------------
__global__ __launch_bounds__(256, 3) void attn_kernel(
    const u16* __restrict__ Qb, const u16* __restrict__ KT,
    const u16* __restrict__ VTg, u16* __restrict__ valsb)
{
    __shared__ __align__(16) u16 KV[2][8192];   // [buf][ K 4096 | V 4096 ] u16
    __shared__ __align__(16) float EX[4352];    // exchange / transpose scratch

    const int tid  = threadIdx.x;
    const int w    = tid >> 6;
    const int lane = tid & 63;
    const int quad = lane >> 4;
    const int l16  = lane & 15;
    const int HD = 1024;

    const int id = blockIdx.x;
    const int h  = (id & 7) * 2 + ((id >> 3) & 1);   // 2 heads per XCD -> L2-local KV
    const int qb = 63 - (id >> 4);                   // long blocks first

    const u16* kt = KT  + (size_t)h * 262144;
    const u16* vt = VTg + (size_t)h * 262144;

    const int wq = w >> 1;     // q half owned (32 rows)
    const int wk = w & 1;      // key half owned (32 keys)

    // swizzled per-lane DMA source offset within a 1KB (16-row) span
    const int dmaoff = (lane >> 2) * 32 + ((lane & 3) ^ ((lane >> 3) & 3)) * 8;
    const int csw = (quad ^ ((l16 >> 1) & 3)) * 8;   // swizzled read chunk

    // ones A-fragment for the denominator MFMA
    bf16x8 ones;
    #pragma unroll
    for (int i = 0; i < 8; i++) ones[i] = (short)0x3F80;   // bf16 1.0
    const f32x4 seed = { -23.0831204f, -23.0831204f, -23.0831204f, -23.0831204f };

    // Q B-frags for this wave's 32 q rows (2 groups x 2 dk halves)
    bf16x8 bq[2][2];
    #pragma unroll
    for (int qt = 0; qt < 2; qt++) {
        const size_t qrow = (size_t)(qb * 64 + wq * 32 + qt * 16 + l16);
        bq[qt][0] = *(const bf16x8*)&Qb[qrow * HD + h * 64 + quad * 8];
        bq[qt][1] = *(const bf16x8*)&Qb[qrow * HD + h * 64 + 32 + quad * 8];
    }

    f32x4 o[2][4];
    #pragma unroll
    for (int i = 0; i < 2; i++)
        #pragma unroll
        for (int j = 0; j < 4; j++) o[i][j] = 0.f;
    f32x4 ls_acc[2];
    ls_acc[0] = 0.f;
    ls_acc[1] = 0.f;

    // prologue DMA: tile 0 -> buf 0
    #pragma unroll
    for (int i = 0; i < 2; i++) {
        gl_lds16(kt + i * 2048 + w * 512 + dmaoff, &KV[0][i * 2048 + w * 512]);
        gl_lds16(vt + i * 2048 + w * 512 + dmaoff, &KV[0][4096 + i * 2048 + w * 512]);
    }

    for (int kb = 0; kb <= qb; kb++) {
        __syncthreads();  // DMA for kb drained; buf[(kb+1)&1] free
        if (kb < qb) {
            const int nb = (kb + 1) & 1;
            const u16* ksrc = kt + (size_t)(kb + 1) * 4096;
            const u16* vsrc = vt + (size_t)(kb + 1) * 4096;
            #pragma unroll
            for (int i = 0; i < 2; i++) {
                gl_lds16(ksrc + i * 2048 + w * 512 + dmaoff, &KV[nb][i * 2048 + w * 512]);
                gl_lds16(vsrc + i * 2048 + w * 512 + dmaoff, &KV[nb][4096 + i * 2048 + w * 512]);
            }
        }
        const u16* Ksb = &KV[kb & 1][0];
        const u16* Vsb = &KV[kb & 1][4096];

        // K frags: only this wave's 32-key half (both dk halves)
        bf16x8 ak[2][2];
        #pragma unroll
        for (int kt2 = 0; kt2 < 2; kt2++) {
            const int krow = wk * 32 + kt2 * 16 + l16;
            ak[kt2][0] = *(const bf16x8*)&Ksb[krow * 32 + csw];
            ak[kt2][1] = *(const bf16x8*)&Ksb[2048 + krow * 32 + csw];
        }

        // S^T = K * Q^T (exp2 domain, bias seeded into accumulator)
        f32x4 s[2][2];
        #pragma unroll
        for (int qt = 0; qt < 2; qt++)
            #pragma unroll
            for (int kt2 = 0; kt2 < 2; kt2++) {
                f32x4 z4 = seed;
                z4 = __builtin_amdgcn_mfma_f32_16x16x32_bf16(ak[kt2][0], bq[qt][0], z4, 0, 0, 0);
                s[qt][kt2] = __builtin_amdgcn_mfma_f32_16x16x32_bf16(ak[kt2][1], bq[qt][1], z4, 0, 0, 0);
            }

        if (kb == qb) {  // diagonal: mask key > q
            #pragma unroll
            for (int qt = 0; qt < 2; qt++)
                #pragma unroll
                for (int kt2 = 0; kt2 < 2; kt2++)
                    #pragma unroll
                    for (int r = 0; r < 4; r++)
                        if (wk * 32 + kt2 * 16 + quad * 4 + r > wq * 32 + qt * 16 + l16)
                            s[qt][kt2][r] = -1e30f;
        }

        // V frags (this wave's key half) issued before exp so lgkmcnt hides
        bf16x8 av[4];
        #pragma unroll
        for (int nv = 0; nv < 4; nv++)
            av[nv] = *(const bf16x8*)&Vsb[wk * 2048 + (nv * 16 + l16) * 32 + csw];

        // p = exp2(s): one v_exp_f32 per element, no prologue VALU
        #pragma unroll
        for (int qt = 0; qt < 2; qt++)
            #pragma unroll
            for (int kt2 = 0; kt2 < 2; kt2++)
                #pragma unroll
                for (int r = 0; r < 4; r++)
                    s[qt][kt2][r] = EXP2(s[qt][kt2][r]);

        bf16x8 bp[2];
        #pragma unroll
        for (int qt = 0; qt < 2; qt++) {
            bf16x8 b = { f32_to_bf16_trunc(s[qt][0][0]), f32_to_bf16_trunc(s[qt][0][1]),
                         f32_to_bf16_trunc(s[qt][0][2]), f32_to_bf16_trunc(s[qt][0][3]),
                         f32_to_bf16_trunc(s[qt][1][0]), f32_to_bf16_trunc(s[qt][1][1]),
                         f32_to_bf16_trunc(s[qt][1][2]), f32_to_bf16_trunc(s[qt][1][3]) };
            bp[qt] = b;
        }

        // denominator via matrix pipe: ls_acc[qt] += ones x P
        #pragma unroll
        for (int qt = 0; qt < 2; qt++)
            ls_acc[qt] = __builtin_amdgcn_mfma_f32_16x16x32_bf16(
                ones, bp[qt], ls_acc[qt], 0, 0, 0);

        // 8 independent accumulator chains
        #pragma unroll
        for (int nv = 0; nv < 4; nv++)
            #pragma unroll
            for (int qt = 0; qt < 2; qt++)
                o[qt][nv] = __builtin_amdgcn_mfma_f32_16x16x32_bf16(
                    av[nv], bp[qt], o[qt][nv], 0, 0, 0);
    }

    // ---- epilogue: combine key-half partials across the wave pair ----
    // ls_acc rows are all identical (ones x P) -> per-lane denominator
    // for q row l16 of group qt is ls_acc[qt][0]; no shfl needed.
    const float lsum0 = ls_acc[0][0];
    const float lsum1 = ls_acc[1][0];

    // wave keeps q-group wk, sends q-group wk^1 to partner wave (w^1).
    // All register indices static (wave-uniform branch on wk).
    float* my = EX + (w * 64 + lane) * 17;
    if (wk == 0) {
        #pragma unroll
        for (int nv = 0; nv < 4; nv++) *(f32x4*)&my[nv * 4] = o[1][nv];
        my[16] = lsum1;
    } else {
        #pragma unroll
        for (int nv = 0; nv < 4; nv++) *(f32x4*)&my[nv * 4] = o[0][nv];
        my[16] = lsum0;
    }
    __syncthreads();   // exchange visible
    const float* pr = EX + ((w ^ 1) * 64 + lane) * 17;
    f32x4 fin[4];
    float denom;
    if (wk == 0) {
        #pragma unroll
        for (int nv = 0; nv < 4; nv++) fin[nv] = o[0][nv] + *(const f32x4*)&pr[nv * 4];
        denom = lsum0 + pr[16];
    } else {
        #pragma unroll
        for (int nv = 0; nv < 4; nv++) fin[nv] = o[1][nv] + *(const f32x4*)&pr[nv * 4];
        denom = lsum1 + pr[16];
    }
    const float inv = 1.f / denom;
    __syncthreads();   // exchange reads done; EX reusable as scratch

    // wave-private transpose scratch: 16 rows x 68 floats
    float* myOw = EX + w * 1088;
    #pragma unroll
    for (int nv = 0; nv < 4; nv++)
        #pragma unroll
        for (int r = 0; r < 4; r++)
            myOw[l16 * 68 + nv * 16 + quad * 4 + r] = fin[nv][r] * inv;
    #pragma unroll
    for (int i = 0; i < 4; i++) {
        int row = i * 4 + quad;   // q row within this wave's owned 16
        f32x4 vv = *(const f32x4*)&myOw[row * 68 + l16 * 4];
        u16x4 u = { f32_to_bf16(vv[0]), f32_to_bf16(vv[1]), f32_to_bf16(vv[2]), f32_to_bf16(vv[3]) };
        *(u16x4*)&valsb[(size_t)(qb * 64 + wq * 32 + wk * 16 + row) * HD + h * 64 + l16 * 4] = u;
    }
}

// ---------------------------------------------------------------------------
// ws layout (u16 idx): qc 0 | kc 4M | vc 8M | wqc 12M | wkc 13M | wvc 14M |
// woc 15M | Qb 16M | KT 20M | VT 24M | trig tables 28M (if ws allows).
// valsb reuses qc. Base 56 MiB + 1 MiB tables.
// ---------------------------------------------------------------------------
extern "C" void kernel_launch(void* const* d_in, const int* in_sizes, int n_in,
                              void* d_out, int out_size, void* d_ws, size_t ws_size,
                              hipStream_t stream) {
    const float* q     = (const float*)d_in[0];
    const float* k     = (const float*)d_in[1];
    const float* v     = (const float*)d_in[2];
    const float* freqs = (const float*)d_in[4];
    const float* wq    = (const float*)d_in[5];
    const float* wk    = (const float*)d_in[6];
    const float* wv    = (const float*)d_in[7];
    const float* wo    = (const float*)d_in[8];

    u16* B = (u16*)d_ws;
    u16* qc  = B;
    u16* kc  = B + (size_t)4194304;
    u16* vc  = B + (size_t)8388608;
    u16* wqc = B + (size_t)12582912;
    u16* wkc = B + (size_t)13631488;
    u16* wvc = B + (size_t)14680064;
    u16* woc = B + (size_t)15728640;
    u16* Qb  = B + (size_t)16777216;
    u16* KT  = B + (size_t)20971520;
    u16* VT  = B + (size_t)25165824;
    u16* valsb = qc;   // qc dead after gemm_rope reads it

    // trig tables after VT: cos [131072 floats] then sin [131072 floats]
    const size_t tab_off_u16 = 29360128;                 // byte 58720256
    const size_t need_bytes  = 58720256 + 2 * 131072 * sizeof(float);
    float* csT = (ws_size >= need_bytes) ? (float*)(B + tab_off_u16) : (float*)0;

    CastArgs ca;
    ca.src[0] = q;  ca.dst[0] = qc;  ca.n4[0] = 1048576;
    ca.src[1] = k;  ca.dst[1] = kc;  ca.n4[1] = 1048576;
    ca.src[2] = v;  ca.dst[2] = vc;  ca.n4[2] = 1048576;
    ca.src[3] = wq; ca.dst[3] = wqc; ca.n4[3] = 262144;
    ca.src[4] = wk; ca.dst[4] = wkc; ca.n4[4] = 262144;
    ca.src[5] = wv; ca.dst[5] = wvc; ca.n4[5] = 262144;
    ca.src[6] = wo; ca.dst[6] = woc; ca.n4[6] = 262144;
    ca.src[7] = freqs; ca.dst[7] = (u16*)csT; ca.n4[7] = csT ? 32768 : 0;
    cast_kernel<<<dim3(1024, 8), 256, 0, stream>>>(ca);

    gemm_rope<<<dim3(32, 8, 3), 256, 0, stream>>>(
        qc, kc, vc, wqc, wkc, wvc, Qb, KT, VT, freqs, csT);

    attn_kernel<<<dim3(1024), 256, 0, stream>>>(Qb, KT, VT, valsb);

    gemm_out<<<dim3(64, 8), 256, 0, stream>>>(valsb, woc, (float*)d_out);
}

// Round 14
// 258.718 us; speedup vs baseline: 1.0482x; 1.0068x over previous
//
#include <hip/hip_runtime.h>

typedef unsigned short u16;
typedef unsigned int u32;
typedef short bf16x8 __attribute__((ext_vector_type(8)));
typedef float f32x4 __attribute__((ext_vector_type(4)));
typedef unsigned short u16x4 __attribute__((ext_vector_type(4)));
typedef unsigned short u16x8 __attribute__((ext_vector_type(8)));

__device__ __forceinline__ u16 f32_to_bf16(float f) {
    u32 u = __float_as_uint(f);
    u += 0x7FFFu + ((u >> 16) & 1u);
    return (u16)(u >> 16);
}
// truncating cast (p in [0,1], P-matrix only)
__device__ __forceinline__ short f32_to_bf16_trunc(float f) {
    return (short)(__float_as_uint(f) >> 16);
}

// native exp2 (v_exp_f32); fallback via __expf if builtin missing
#if __has_builtin(__builtin_amdgcn_exp2f)
#define EXP2(x) __builtin_amdgcn_exp2f(x)
#else
#define EXP2(x) __expf((x) * 0.69314718056f)
#endif

// async global->LDS, 16B per lane; lds pointer must be wave-uniform
__device__ __forceinline__ void gl_lds16(const u16* g, u16* l) {
    __builtin_amdgcn_global_load_lds(
        (const __attribute__((address_space(1))) u32*)g,
        (__attribute__((address_space(3))) u32*)l, 16, 0, 0);
}

// Bank-conflict swizzle for 64B-row LDS tiles read as (row*32 + chunk*8) u16:
// physical chunk = logical chunk ^ ((row>>1)&3). Folded into the DMA *source*
// address (per-lane), so LDS writes stay contiguous.

// ---------------------------------------------------------------------------
// bulk fp32 -> bf16 cast; slice y==7 builds the RoPE cos/sin tables
// ---------------------------------------------------------------------------
struct CastArgs {
    const float* src[8];
    u16* dst[8];
    int n4[8];
};

__global__ __launch_bounds__(256) void cast_kernel(CastArgs a) {
    const int y = blockIdx.y;
    const int n4 = a.n4[y];
    if (y == 7) {
        // RoPE trig tables: dst[7] = cos table (fp32), sin table right after.
        const float* s = a.src[7];
        float* c  = (float*)a.dst[7];
        float* sn = c + 131072;
        for (int i = blockIdx.x * blockDim.x + threadIdx.x; i < n4; i += gridDim.x * blockDim.x) {
            f32x4 v = *(const f32x4*)&s[(size_t)i * 4];
            f32x4 cv, sv;
            #pragma unroll
            for (int j = 0; j < 4; j++) {
                float ss, cc;
                __sincosf(v[j], &ss, &cc);
                sv[j] = ss; cv[j] = cc;
            }
            *(f32x4*)&c[(size_t)i * 4]  = cv;
            *(f32x4*)&sn[(size_t)i * 4] = sv;
        }
        return;
    }
    const float* s = a.src[y];
    u16* d = a.dst[y];
    for (int i = blockIdx.x * blockDim.x + threadIdx.x; i < n4; i += gridDim.x * blockDim.x) {
        f32x4 v = *(const f32x4*)&s[(size_t)i * 4];
        u16x4 o = { f32_to_bf16(v[0]), f32_to_bf16(v[1]), f32_to_bf16(v[2]), f32_to_bf16(v[3]) };
        *(u16x4*)&d[(size_t)i * 4] = o;
    }
}

#define GK 1024
#define GN 1024
#define GM 4096

// ---------------------------------------------------------------------------
// QKV projection GEMM + RoPE. 128x128 tile, BK=32, grid (32 m, 8 n, 3 z).
// Single-barrier double-buffer main loop (round-12 verified, -20% vs the
// two-barrier version). z=0 Q: [t][HD] bf16 scaled 0.125*log2(e);
// z=1 K: KT[h][kb][ks][kl][32]; z=2 V: VT[h][kb][ks][dv][32'].
// RoPE trig from precomputed tables (csT) with in-line fallback.
// ---------------------------------------------------------------------------
__global__ __launch_bounds__(256) void gemm_rope(
    const u16* __restrict__ A0, const u16* __restrict__ A1, const u16* __restrict__ A2,
    const u16* __restrict__ W0, const u16* __restrict__ W1, const u16* __restrict__ W2,
    u16* __restrict__ C0, u16* __restrict__ C1, u16* __restrict__ C2,
    const float* __restrict__ freqs, const float* __restrict__ csT)
{
    __shared__ u16 SM[16384];   // [buf][ A 4096 | B 4096 ] u16, double-buffered

    const int z = blockIdx.z;
    const u16* A = (z == 0) ? A0 : ((z == 1) ? A1 : A2);
    const u16* W = (z == 0) ? W0 : ((z == 1) ? W1 : W2);
    u16* Cb      = (z == 0) ? C0 : ((z == 1) ? C1 : C2);
    const float ascale = (z == 0) ? 0.18033688f : 1.0f;   // 0.125 * log2(e)

    const int tid  = threadIdx.x;
    const int w    = tid >> 6;
    const int lane = tid & 63;
    const int quad = lane >> 4;
    const int l16  = lane & 15;
    const int m0 = blockIdx.x * 128;
    const int n0 = blockIdx.y * 128;
    const int wm = (w >> 1) * 64;
    const int wn = (w & 1) * 64;

    const int sr = tid >> 2;
    const int sc = (((tid & 3) ^ ((tid >> 3) & 3))) * 8;   // swizzled source chunk
    const size_t aoff0 = (size_t)(m0 + sr) * GK + sc;
    const size_t aoff1 = aoff0 + (size_t)64 * GK;
    const size_t boff0 = (size_t)(n0 + sr) * GK + sc;
    const size_t boff1 = boff0 + (size_t)64 * GK;

    const int csw = (quad ^ ((l16 >> 1) & 3)) * 8;          // swizzled read chunk

    f32x4 acc[4][4];
    for (int i = 0; i < 4; i++)
        for (int j = 0; j < 4; j++) acc[i][j] = 0.f;

    // prologue: stage tile 0 -> buf 0
    {
        u16* Ab = SM;
        gl_lds16(A + aoff0, &Ab[w * 512]);
        gl_lds16(A + aoff1, &Ab[2048 + w * 512]);
        gl_lds16(W + boff0, &Ab[4096 + w * 512]);
        gl_lds16(W + boff1, &Ab[4096 + 2048 + w * 512]);
    }

    for (int it = 0; it < 32; ++it) {
        __syncthreads();   // DMA for tile it drained; buf^1 free for prefetch
        if (it < 31) {
            const int k0 = (it + 1) * 32;
            u16* Ab = SM + ((it + 1) & 1) * 8192;
            gl_lds16(A + aoff0 + k0, &Ab[w * 512]);
            gl_lds16(A + aoff1 + k0, &Ab[2048 + w * 512]);
            gl_lds16(W + boff0 + k0, &Ab[4096 + w * 512]);
            gl_lds16(W + boff1 + k0, &Ab[4096 + 2048 + w * 512]);
        }
        const u16* As = SM + (it & 1) * 8192;
        const u16* Bs = As + 4096;

        bf16x8 af[4], bfr[4];
        for (int t = 0; t < 4; t++) {
            af[t]  = *(const bf16x8*)&As[(wm + t * 16 + l16) * 32 + csw];
            bfr[t] = *(const bf16x8*)&Bs[(wn + t * 16 + l16) * 32 + csw];
        }
        for (int mt = 0; mt < 4; mt++)
            for (int nt = 0; nt < 4; nt++)
                acc[mt][nt] = __builtin_amdgcn_mfma_f32_16x16x32_bf16(
                    af[mt], bfr[nt], acc[mt][nt], 0, 0, 0);
    }
    __syncthreads();   // all compute done; SM dead -> reusable as scratch
    // per-wave scratch (wave-private)
    u16* tr = SM + w * 1152;  // 16 rows x 72 u16

    const int hh = (n0 + wn) >> 6;
    const size_t tb = (size_t)hh * 262144 + (size_t)((m0 + wm) >> 6) * 4096;
    const float* snT = csT ? (csT + 131072) : (const float*)0;

    if (z != 2) {
        for (int mt = 0; mt < 4; mt++) {
            #pragma unroll
            for (int r = 0; r < 4; r++) {
                int m = m0 + wm + mt * 16 + quad * 4 + r;
                float v0 = acc[mt][0][r];
                float v1 = acc[mt][1][r];
                float s0, c0, s1, c1;
                if (csT) {
                    c0 = csT[m * 32 + l16];      s0 = snT[m * 32 + l16];
                    c1 = csT[m * 32 + 16 + l16]; s1 = snT[m * 32 + 16 + l16];
                } else {
                    __sincosf(freqs[m * 32 + l16], &s0, &c0);
                    __sincosf(freqs[m * 32 + 16 + l16], &s1, &c1);
                }
                int row = quad * 4 + r;
                tr[row * 72 + l16]      = f32_to_bf16((v0 * c0 - v1 * s0) * ascale);
                tr[row * 72 + 16 + l16] = f32_to_bf16((v1 * c1 + v0 * s1) * ascale);
                tr[row * 72 + 32 + l16] = f32_to_bf16(acc[mt][2][r] * ascale);
                tr[row * 72 + 48 + l16] = f32_to_bf16(acc[mt][3][r] * ascale);
            }
            // wave-private transpose read: lane -> row l16, cols quad*16..+16
            u16x8 va = *(const u16x8*)&tr[l16 * 72 + quad * 16];
            u16x8 vb = *(const u16x8*)&tr[l16 * 72 + quad * 16 + 8];
            if (z == 0) {
                size_t base = (size_t)(m0 + wm + mt * 16 + l16) * GN + n0 + wn + quad * 16;
                *(u16x8*)&Cb[base]     = va;
                *(u16x8*)&Cb[base + 8] = vb;
            } else {
                // K half-split: dk = quad*16 + c -> half ks = quad>>1, within = (quad&1)*16 + c
                size_t base = tb + (size_t)(quad >> 1) * 2048
                            + (size_t)(mt * 16 + l16) * 32 + (quad & 1) * 16;
                *(u16x8*)&Cb[base]     = va;
                *(u16x8*)&Cb[base + 8] = vb;
            }
        }
    } else {
        // V: VT[h][kb][ks][dv][32'], kappa within each 32-key half
        for (int mt = 0; mt < 4; mt++) {
            float o0[4], o1[4];
            for (int r = 0; r < 4; r++) {
                int m = m0 + wm + mt * 16 + quad * 4 + r;
                float v0 = acc[mt][0][r];
                float v1 = acc[mt][1][r];
                float s0, c0, s1, c1;
                if (csT) {
                    c0 = csT[m * 32 + l16];      s0 = snT[m * 32 + l16];
                    c1 = csT[m * 32 + 16 + l16]; s1 = snT[m * 32 + 16 + l16];
                } else {
                    __sincosf(freqs[m * 32 + l16], &s0, &c0);
                    __sincosf(freqs[m * 32 + 16 + l16], &s1, &c1);
                }
                o0[r] = v0 * c0 - v1 * s0;
                o1[r] = v1 * c1 + v0 * s1;
            }
            const int ks = mt >> 1;                       // key half
            const int sl = 4 * (mt & 1) + 8 * quad;       // slot within half (r adds 0..3)
            const size_t hb = tb + (size_t)ks * 2048 + sl;
            u16x4 u;
            u = { f32_to_bf16(o0[0]), f32_to_bf16(o0[1]), f32_to_bf16(o0[2]), f32_to_bf16(o0[3]) };
            *(u16x4*)&Cb[hb + (size_t)l16 * 32] = u;
            u = { f32_to_bf16(o1[0]), f32_to_bf16(o1[1]), f32_to_bf16(o1[2]), f32_to_bf16(o1[3]) };
            *(u16x4*)&Cb[hb + (size_t)(16 + l16) * 32] = u;
            u = { f32_to_bf16(acc[mt][2][0]), f32_to_bf16(acc[mt][2][1]),
                  f32_to_bf16(acc[mt][2][2]), f32_to_bf16(acc[mt][2][3]) };
            *(u16x4*)&Cb[hb + (size_t)(32 + l16) * 32] = u;
            u = { f32_to_bf16(acc[mt][3][0]), f32_to_bf16(acc[mt][3][1]),
                  f32_to_bf16(acc[mt][3][2]), f32_to_bf16(acc[mt][3][3]) };
            *(u16x4*)&Cb[hb + (size_t)(48 + l16) * 32] = u;
        }
    }
}

// ---------------------------------------------------------------------------
// Output projection GEMM. Tile 64x128, grid (64 m, 8 n) = 512 blocks = 2/CU.
// Single-barrier double-buffer protocol (round-12 verified).
// ---------------------------------------------------------------------------
__global__ __launch_bounds__(256) void gemm_out(
    const u16* __restrict__ A, const u16* __restrict__ W, float* __restrict__ C)
{
    __shared__ u16 SM[12288];  // [buf][ A 2048 | B 4096 ] u16, double-buffered

    const int tid  = threadIdx.x;
    const int w    = tid >> 6;
    const int lane = tid & 63;
    const int quad = lane >> 4;
    const int l16  = lane & 15;
    const int m0 = blockIdx.x * 64;
    const int n0 = blockIdx.y * 128;
    const int wm = (w >> 1) * 32;
    const int wn = (w & 1) * 64;

    const int sr = tid >> 2;
    const int sc = (((tid & 3) ^ ((tid >> 3) & 3))) * 8;   // swizzled source chunk
    const size_t aoff  = (size_t)(m0 + sr) * GK + sc;
    const size_t boff0 = (size_t)(n0 + sr) * GK + sc;
    const size_t boff1 = boff0 + (size_t)64 * GK;

    const int csw = (quad ^ ((l16 >> 1) & 3)) * 8;

    f32x4 acc[2][4];
    for (int i = 0; i < 2; i++)
        for (int j = 0; j < 4; j++) acc[i][j] = 0.f;

    // prologue: stage tile 0 -> buf 0
    {
        u16* Ab = SM;
        gl_lds16(A + aoff,  &Ab[w * 512]);
        gl_lds16(W + boff0, &Ab[2048 + w * 512]);
        gl_lds16(W + boff1, &Ab[2048 + 2048 + w * 512]);
    }

    for (int it = 0; it < 32; ++it) {
        __syncthreads();   // DMA for tile it drained; buf^1 free
        if (it < 31) {
            const int k0 = (it + 1) * 32;
            u16* Ab = SM + ((it + 1) & 1) * 6144;
            gl_lds16(A + aoff + k0,  &Ab[w * 512]);
            gl_lds16(W + boff0 + k0, &Ab[2048 + w * 512]);
            gl_lds16(W + boff1 + k0, &Ab[2048 + 2048 + w * 512]);
        }
        const u16* As = SM + (it & 1) * 6144;
        const u16* Bs = As + 2048;

        bf16x8 af[2], bfr[4];
        for (int t = 0; t < 2; t++)
            af[t] = *(const bf16x8*)&As[(wm + t * 16 + l16) * 32 + csw];
        for (int t = 0; t < 4; t++)
            bfr[t] = *(const bf16x8*)&Bs[(wn + t * 16 + l16) * 32 + csw];
        for (int mt = 0; mt < 2; mt++)
            for (int nt = 0; nt < 4; nt++)
                acc[mt][nt] = __builtin_amdgcn_mfma_f32_16x16x32_bf16(
                    af[mt], bfr[nt], acc[mt][nt], 0, 0, 0);
    }
    __syncthreads();   // all compute done; SM dead -> reusable as scratch

    // per-wave fp32 transpose scratch: 16 rows x 68 floats
    float* tr = (float*)SM + w * 1088;
    for (int mt = 0; mt < 2; mt++) {
        #pragma unroll
        for (int nt = 0; nt < 4; nt++)
            #pragma unroll
            for (int r = 0; r < 4; r++)
                tr[(quad * 4 + r) * 68 + nt * 16 + l16] = acc[mt][nt][r];
        size_t base = (size_t)(m0 + wm + mt * 16 + l16) * GN + n0 + wn + quad * 16;
        #pragma unroll
        for (int c = 0; c < 4; c++) {
            f32x4 v = *(const f32x4*)&tr[l16 * 68 + quad * 16 + c * 4];
            *(f32x4*)&C[base + c * 4] = v;
        }
    }
}

// ---------------------------------------------------------------------------
// Flash attention, causal. 8-WAVE blocks (512 thr): wave w owns q-quarter
// (w>>1, 16 rows) x key-half (w&1, 32 keys). Per-wave work halves vs the
// 4-wave version (9 MFMAs + 8 exp2 per iter) -> shorter serial chain, and
// LDS 32KB KV + 34.8KB EX caps residency at 2 blocks/CU = 16 waves/CU =
// 4 waves/SIMD (vs 3): +33% TLP inside the PROVEN-SAFE residency regime
// (>=4 small-blocks/CU of this kernel failed nondeterministically in
// rounds 7/8/9 — 2-resident is the safest measured config).
// Grid 1024: one block per (head, 64-row q-block), qb = 63-(id>>4) long-first.
// Staging: waves 0-3 stage K, 4-7 stage V (2 gl_lds16 each), single
// barrier/iter double buffer. exp2-domain softmax (Q pre-scaled 0.125*log2e,
// -16*log2e seeded), denominator via ones-MFMA. Epilogue: pair (w, w^1)
// exchanges key-half partials through dedicated EX (stride 17, odd ->
// conflict-free); output store rows split by wk (0-7 / 8-15).
// XCD locality: h = (id&7)*2 + ((id>>3)&1) keeps 2 heads (2MB KV) per XCD L2.
// ---------------------------------------------------------------------------
__global__ __launch_bounds__(512, 2) void attn_kernel(
    const u16* __restrict__ Qb, const u16* __restrict__ KT,
    const u16* __restrict__ VTg, u16* __restrict__ valsb)
{
    __shared__ __align__(16) u16 KV[2][8192];   // [buf][ K 4096 | V 4096 ] u16
    __shared__ __align__(16) float EX[8704];    // 512 lanes x 17 fl exchange / scratch

    const int tid  = threadIdx.x;
    const int w    = tid >> 6;          // 0..7
    const int lane = tid & 63;
    const int quad = lane >> 4;
    const int l16  = lane & 15;
    const int HD = 1024;

    const int id = blockIdx.x;
    const int h  = (id & 7) * 2 + ((id >> 3) & 1);   // 2 heads per XCD -> L2-local KV
    const int qb = 63 - (id >> 4);                   // long blocks first

    const u16* kt = KT  + (size_t)h * 262144;
    const u16* vt = VTg + (size_t)h * 262144;

    const int wq = w >> 1;     // q quarter owned (16 rows)
    const int wk = w & 1;      // key half owned (32 keys)
    const int wr = w & 3;      // staging slot within K or V region

    // swizzled per-lane DMA source offset within a 1KB (16-row) span
    const int dmaoff = (lane >> 2) * 32 + ((lane & 3) ^ ((lane >> 3) & 3)) * 8;
    const int csw = (quad ^ ((l16 >> 1) & 3)) * 8;   // swizzled read chunk

    // this wave stages K (w<4) or V (w>=4): 2 x 1KB per iter
    const u16* stsrc = (w < 4) ? kt : vt;
    const int  stdst = (w < 4) ? 0 : 4096;

    // ones A-fragment for the denominator MFMA
    bf16x8 ones;
    #pragma unroll
    for (int i = 0; i < 8; i++) ones[i] = (short)0x3F80;   // bf16 1.0
    const f32x4 seed = { -23.0831204f, -23.0831204f, -23.0831204f, -23.0831204f };

    // Q B-frags for this wave's 16 q rows (2 dk halves)
    const size_t qrow = (size_t)(qb * 64 + wq * 16 + l16);
    const bf16x8 bq0 = *(const bf16x8*)&Qb[qrow * HD + h * 64 + quad * 8];
    const bf16x8 bq1 = *(const bf16x8*)&Qb[qrow * HD + h * 64 + 32 + quad * 8];
    const int q_local = wq * 16 + l16;

    f32x4 o[4];
    #pragma unroll
    for (int i = 0; i < 4; i++) o[i] = 0.f;
    f32x4 ls_acc = 0.f;

    // prologue DMA: tile 0 -> buf 0
    gl_lds16(stsrc + wr * 512 + dmaoff,        &KV[0][stdst + wr * 512]);
    gl_lds16(stsrc + 2048 + wr * 512 + dmaoff, &KV[0][stdst + 2048 + wr * 512]);

    for (int kb = 0; kb <= qb; kb++) {
        __syncthreads();  // DMA for kb drained; buf[(kb+1)&1] free
        if (kb < qb) {
            const int nb = (kb + 1) & 1;
            const u16* src = stsrc + (size_t)(kb + 1) * 4096;
            gl_lds16(src + wr * 512 + dmaoff,        &KV[nb][stdst + wr * 512]);
            gl_lds16(src + 2048 + wr * 512 + dmaoff, &KV[nb][stdst + 2048 + wr * 512]);
        }
        const u16* Ksb = &KV[kb & 1][0];
        const u16* Vsb = &KV[kb & 1][4096];

        // K frags: this wave's 32-key half (both dk halves)
        bf16x8 ak[2][2];
        #pragma unroll
        for (int kt2 = 0; kt2 < 2; kt2++) {
            const int krow = wk * 32 + kt2 * 16 + l16;
            ak[kt2][0] = *(const bf16x8*)&Ksb[krow * 32 + csw];
            ak[kt2][1] = *(const bf16x8*)&Ksb[2048 + krow * 32 + csw];
        }

        // S^T = K * Q^T (exp2 domain, bias seeded into accumulator)
        f32x4 s[2];
        #pragma unroll
        for (int kt2 = 0; kt2 < 2; kt2++) {
            f32x4 z4 = seed;
            z4 = __builtin_amdgcn_mfma_f32_16x16x32_bf16(ak[kt2][0], bq0, z4, 0, 0, 0);
            s[kt2] = __builtin_amdgcn_mfma_f32_16x16x32_bf16(ak[kt2][1], bq1, z4, 0, 0, 0);
        }

        if (kb == qb) {  // diagonal: mask key > q
            #pragma unroll
            for (int kt2 = 0; kt2 < 2; kt2++)
                #pragma unroll
                for (int r = 0; r < 4; r++)
                    if (wk * 32 + kt2 * 16 + quad * 4 + r > q_local) s[kt2][r] = -1e30f;
        }

        // V frags (this wave's key half) issued before exp so lgkmcnt hides
        bf16x8 av[4];
        #pragma unroll
        for (int nv = 0; nv < 4; nv++)
            av[nv] = *(const bf16x8*)&Vsb[wk * 2048 + (nv * 16 + l16) * 32 + csw];

        // p = exp2(s): one v_exp_f32 per element
        #pragma unroll
        for (int kt2 = 0; kt2 < 2; kt2++)
            #pragma unroll
            for (int r = 0; r < 4; r++)
                s[kt2][r] = EXP2(s[kt2][r]);

        bf16x8 bp = { f32_to_bf16_trunc(s[0][0]), f32_to_bf16_trunc(s[0][1]),
                      f32_to_bf16_trunc(s[0][2]), f32_to_bf16_trunc(s[0][3]),
                      f32_to_bf16_trunc(s[1][0]), f32_to_bf16_trunc(s[1][1]),
                      f32_to_bf16_trunc(s[1][2]), f32_to_bf16_trunc(s[1][3]) };

        // denominator via matrix pipe: ls_acc += ones x P
        ls_acc = __builtin_amdgcn_mfma_f32_16x16x32_bf16(ones, bp, ls_acc, 0, 0, 0);

        // PV: 4 independent accumulator chains
        #pragma unroll
        for (int nv = 0; nv < 4; nv++)
            o[nv] = __builtin_amdgcn_mfma_f32_16x16x32_bf16(av[nv], bp, o[nv], 0, 0, 0);
    }

    // ---- epilogue: combine key-half partials across the wave pair (w, w^1) ----
    // ls_acc rows identical (ones x P) -> per-lane denominator partial = ls_acc[0].
    const float lsum = ls_acc[0];

    float* my = EX + (w * 64 + lane) * 17;
    #pragma unroll
    for (int nv = 0; nv < 4; nv++) *(f32x4*)&my[nv * 4] = o[nv];
    my[16] = lsum;
    __syncthreads();   // exchange visible
    const float* pr = EX + ((w ^ 1) * 64 + lane) * 17;
    f32x4 fin[4];
    #pragma unroll
    for (int nv = 0; nv < 4; nv++) fin[nv] = o[nv] + *(const f32x4*)&pr[nv * 4];
    const float inv = 1.f / (lsum + pr[16]);
    __syncthreads();   // exchange reads done; EX reusable as scratch

    // wave-private transpose scratch: 16 rows x 68 floats
    float* myOw = EX + w * 1088;
    #pragma unroll
    for (int nv = 0; nv < 4; nv++)
        #pragma unroll
        for (int r = 0; r < 4; r++)
            myOw[l16 * 68 + nv * 16 + quad * 4 + r] = fin[nv][r] * inv;
    // both waves of the pair hold identical fin; split the store by wk
    #pragma unroll
    for (int i = 0; i < 2; i++) {
        int row = (wk * 2 + i) * 4 + quad;   // wk=0: rows 0..7, wk=1: rows 8..15
        f32x4 vv = *(const f32x4*)&myOw[row * 68 + l16 * 4];
        u16x4 u = { f32_to_bf16(vv[0]), f32_to_bf16(vv[1]), f32_to_bf16(vv[2]), f32_to_bf16(vv[3]) };
        *(u16x4*)&valsb[(size_t)(qb * 64 + wq * 16 + row) * HD + h * 64 + l16 * 4] = u;
    }
}

// ---------------------------------------------------------------------------
// ws layout (u16 idx): qc 0 | kc 4M | vc 8M | wqc 12M | wkc 13M | wvc 14M |
// woc 15M | Qb 16M | KT 20M | VT 24M | trig tables 28M (if ws allows).
// valsb reuses qc. Base 56 MiB + 1 MiB tables.
// ---------------------------------------------------------------------------
extern "C" void kernel_launch(void* const* d_in, const int* in_sizes, int n_in,
                              void* d_out, int out_size, void* d_ws, size_t ws_size,
                              hipStream_t stream) {
    const float* q     = (const float*)d_in[0];
    const float* k     = (const float*)d_in[1];
    const float* v     = (const float*)d_in[2];
    const float* freqs = (const float*)d_in[4];
    const float* wq    = (const float*)d_in[5];
    const float* wk    = (const float*)d_in[6];
    const float* wv    = (const float*)d_in[7];
    const float* wo    = (const float*)d_in[8];

    u16* B = (u16*)d_ws;
    u16* qc  = B;
    u16* kc  = B + (size_t)4194304;
    u16* vc  = B + (size_t)8388608;
    u16* wqc = B + (size_t)12582912;
    u16* wkc = B + (size_t)13631488;
    u16* wvc = B + (size_t)14680064;
    u16* woc = B + (size_t)15728640;
    u16* Qb  = B + (size_t)16777216;
    u16* KT  = B + (size_t)20971520;
    u16* VT  = B + (size_t)25165824;
    u16* valsb = qc;   // qc dead after gemm_rope reads it

    // trig tables after VT: cos [131072 floats] then sin [131072 floats]
    const size_t tab_off_u16 = 29360128;                 // byte 58720256
    const size_t need_bytes  = 58720256 + 2 * 131072 * sizeof(float);
    float* csT = (ws_size >= need_bytes) ? (float*)(B + tab_off_u16) : (float*)0;

    CastArgs ca;
    ca.src[0] = q;  ca.dst[0] = qc;  ca.n4[0] = 1048576;
    ca.src[1] = k;  ca.dst[1] = kc;  ca.n4[1] = 1048576;
    ca.src[2] = v;  ca.dst[2] = vc;  ca.n4[2] = 1048576;
    ca.src[3] = wq; ca.dst[3] = wqc; ca.n4[3] = 262144;
    ca.src[4] = wk; ca.dst[4] = wkc; ca.n4[4] = 262144;
    ca.src[5] = wv; ca.dst[5] = wvc; ca.n4[5] = 262144;
    ca.src[6] = wo; ca.dst[6] = woc; ca.n4[6] = 262144;
    ca.src[7] = freqs; ca.dst[7] = (u16*)csT; ca.n4[7] = csT ? 32768 : 0;
    cast_kernel<<<dim3(1024, 8), 256, 0, stream>>>(ca);

    gemm_rope<<<dim3(32, 8, 3), 256, 0, stream>>>(
        qc, kc, vc, wqc, wkc, wvc, Qb, KT, VT, freqs, csT);

    attn_kernel<<<dim3(1024), 512, 0, stream>>>(Qb, KT, VT, valsb);

    gemm_out<<<dim3(64, 8), 256, 0, stream>>>(valsb, woc, (float*)d_out);
}

// Round 15
// 256.345 us; speedup vs baseline: 1.0579x; 1.0093x over previous
//
#include <hip/hip_runtime.h>

typedef unsigned short u16;
typedef unsigned int u32;
typedef short bf16x8 __attribute__((ext_vector_type(8)));
typedef float f32x4 __attribute__((ext_vector_type(4)));
typedef unsigned short u16x4 __attribute__((ext_vector_type(4)));
typedef unsigned short u16x8 __attribute__((ext_vector_type(8)));

__device__ __forceinline__ u16 f32_to_bf16(float f) {
    u32 u = __float_as_uint(f);
    u += 0x7FFFu + ((u >> 16) & 1u);
    return (u16)(u >> 16);
}
// truncating cast (p in [0,1], P-matrix only)
__device__ __forceinline__ short f32_to_bf16_trunc(float f) {
    return (short)(__float_as_uint(f) >> 16);
}

// native exp2 (v_exp_f32); fallback via __expf if builtin missing
#if __has_builtin(__builtin_amdgcn_exp2f)
#define EXP2(x) __builtin_amdgcn_exp2f(x)
#else
#define EXP2(x) __expf((x) * 0.69314718056f)
#endif

// async global->LDS, 16B per lane; lds pointer must be wave-uniform
__device__ __forceinline__ void gl_lds16(const u16* g, u16* l) {
    __builtin_amdgcn_global_load_lds(
        (const __attribute__((address_space(1))) u32*)g,
        (__attribute__((address_space(3))) u32*)l, 16, 0, 0);
}

// Bank-conflict swizzle for 64B-row LDS tiles read as (row*32 + chunk*8) u16:
// physical chunk = logical chunk ^ ((row>>1)&3). Folded into the DMA *source*
// address (per-lane), so LDS writes stay contiguous.

// ---------------------------------------------------------------------------
// bulk fp32 -> bf16 cast; slice y==7 builds the RoPE cos/sin tables
// ---------------------------------------------------------------------------
struct CastArgs {
    const float* src[8];
    u16* dst[8];
    int n4[8];
};

__global__ __launch_bounds__(256) void cast_kernel(CastArgs a) {
    const int y = blockIdx.y;
    const int n4 = a.n4[y];
    if (y == 7) {
        // RoPE trig tables: dst[7] = cos table (fp32), sin table right after.
        const float* s = a.src[7];
        float* c  = (float*)a.dst[7];
        float* sn = c + 131072;
        for (int i = blockIdx.x * blockDim.x + threadIdx.x; i < n4; i += gridDim.x * blockDim.x) {
            f32x4 v = *(const f32x4*)&s[(size_t)i * 4];
            f32x4 cv, sv;
            #pragma unroll
            for (int j = 0; j < 4; j++) {
                float ss, cc;
                __sincosf(v[j], &ss, &cc);
                sv[j] = ss; cv[j] = cc;
            }
            *(f32x4*)&c[(size_t)i * 4]  = cv;
            *(f32x4*)&sn[(size_t)i * 4] = sv;
        }
        return;
    }
    const float* s = a.src[y];
    u16* d = a.dst[y];
    for (int i = blockIdx.x * blockDim.x + threadIdx.x; i < n4; i += gridDim.x * blockDim.x) {
        f32x4 v = *(const f32x4*)&s[(size_t)i * 4];
        u16x4 o = { f32_to_bf16(v[0]), f32_to_bf16(v[1]), f32_to_bf16(v[2]), f32_to_bf16(v[3]) };
        *(u16x4*)&d[(size_t)i * 4] = o;
    }
}

#define GK 1024
#define GN 1024
#define GM 4096

// ---------------------------------------------------------------------------
// QKV projection GEMM + RoPE. 128x128 tile, BK=32, grid (32 m, 8 n, 3 z).
// Single-barrier double-buffer main loop (round-12 verified, -20% vs the
// two-barrier version). z=0 Q: [t][HD] bf16 scaled 0.125*log2(e);
// z=1 K: KT[h][kb][ks][kl][32]; z=2 V: VT[h][kb][ks][dv][32'].
// RoPE trig from precomputed tables (csT) with in-line fallback.
// ---------------------------------------------------------------------------
__global__ __launch_bounds__(256) void gemm_rope(
    const u16* __restrict__ A0, const u16* __restrict__ A1, const u16* __restrict__ A2,
    const u16* __restrict__ W0, const u16* __restrict__ W1, const u16* __restrict__ W2,
    u16* __restrict__ C0, u16* __restrict__ C1, u16* __restrict__ C2,
    const float* __restrict__ freqs, const float* __restrict__ csT)
{
    __shared__ u16 SM[16384];   // [buf][ A 4096 | B 4096 ] u16, double-buffered

    const int z = blockIdx.z;
    const u16* A = (z == 0) ? A0 : ((z == 1) ? A1 : A2);
    const u16* W = (z == 0) ? W0 : ((z == 1) ? W1 : W2);
    u16* Cb      = (z == 0) ? C0 : ((z == 1) ? C1 : C2);
    const float ascale = (z == 0) ? 0.18033688f : 1.0f;   // 0.125 * log2(e)

    const int tid  = threadIdx.x;
    const int w    = tid >> 6;
    const int lane = tid & 63;
    const int quad = lane >> 4;
    const int l16  = lane & 15;
    const int m0 = blockIdx.x * 128;
    const int n0 = blockIdx.y * 128;
    const int wm = (w >> 1) * 64;
    const int wn = (w & 1) * 64;

    const int sr = tid >> 2;
    const int sc = (((tid & 3) ^ ((tid >> 3) & 3))) * 8;   // swizzled source chunk
    const size_t aoff0 = (size_t)(m0 + sr) * GK + sc;
    const size_t aoff1 = aoff0 + (size_t)64 * GK;
    const size_t boff0 = (size_t)(n0 + sr) * GK + sc;
    const size_t boff1 = boff0 + (size_t)64 * GK;

    const int csw = (quad ^ ((l16 >> 1) & 3)) * 8;          // swizzled read chunk

    f32x4 acc[4][4];
    for (int i = 0; i < 4; i++)
        for (int j = 0; j < 4; j++) acc[i][j] = 0.f;

    // prologue: stage tile 0 -> buf 0
    {
        u16* Ab = SM;
        gl_lds16(A + aoff0, &Ab[w * 512]);
        gl_lds16(A + aoff1, &Ab[2048 + w * 512]);
        gl_lds16(W + boff0, &Ab[4096 + w * 512]);
        gl_lds16(W + boff1, &Ab[4096 + 2048 + w * 512]);
    }

    for (int it = 0; it < 32; ++it) {
        __syncthreads();   // DMA for tile it drained; buf^1 free for prefetch
        if (it < 31) {
            const int k0 = (it + 1) * 32;
            u16* Ab = SM + ((it + 1) & 1) * 8192;
            gl_lds16(A + aoff0 + k0, &Ab[w * 512]);
            gl_lds16(A + aoff1 + k0, &Ab[2048 + w * 512]);
            gl_lds16(W + boff0 + k0, &Ab[4096 + w * 512]);
            gl_lds16(W + boff1 + k0, &Ab[4096 + 2048 + w * 512]);
        }
        const u16* As = SM + (it & 1) * 8192;
        const u16* Bs = As + 4096;

        bf16x8 af[4], bfr[4];
        for (int t = 0; t < 4; t++) {
            af[t]  = *(const bf16x8*)&As[(wm + t * 16 + l16) * 32 + csw];
            bfr[t] = *(const bf16x8*)&Bs[(wn + t * 16 + l16) * 32 + csw];
        }
        for (int mt = 0; mt < 4; mt++)
            for (int nt = 0; nt < 4; nt++)
                acc[mt][nt] = __builtin_amdgcn_mfma_f32_16x16x32_bf16(
                    af[mt], bfr[nt], acc[mt][nt], 0, 0, 0);
    }
    __syncthreads();   // all compute done; SM dead -> reusable as scratch
    // per-wave scratch (wave-private)
    u16* tr = SM + w * 1152;  // 16 rows x 72 u16

    const int hh = (n0 + wn) >> 6;
    const size_t tb = (size_t)hh * 262144 + (size_t)((m0 + wm) >> 6) * 4096;
    const float* snT = csT ? (csT + 131072) : (const float*)0;

    if (z != 2) {
        for (int mt = 0; mt < 4; mt++) {
            #pragma unroll
            for (int r = 0; r < 4; r++) {
                int m = m0 + wm + mt * 16 + quad * 4 + r;
                float v0 = acc[mt][0][r];
                float v1 = acc[mt][1][r];
                float s0, c0, s1, c1;
                if (csT) {
                    c0 = csT[m * 32 + l16];      s0 = snT[m * 32 + l16];
                    c1 = csT[m * 32 + 16 + l16]; s1 = snT[m * 32 + 16 + l16];
                } else {
                    __sincosf(freqs[m * 32 + l16], &s0, &c0);
                    __sincosf(freqs[m * 32 + 16 + l16], &s1, &c1);
                }
                int row = quad * 4 + r;
                tr[row * 72 + l16]      = f32_to_bf16((v0 * c0 - v1 * s0) * ascale);
                tr[row * 72 + 16 + l16] = f32_to_bf16((v1 * c1 + v0 * s1) * ascale);
                tr[row * 72 + 32 + l16] = f32_to_bf16(acc[mt][2][r] * ascale);
                tr[row * 72 + 48 + l16] = f32_to_bf16(acc[mt][3][r] * ascale);
            }
            // wave-private transpose read: lane -> row l16, cols quad*16..+16
            u16x8 va = *(const u16x8*)&tr[l16 * 72 + quad * 16];
            u16x8 vb = *(const u16x8*)&tr[l16 * 72 + quad * 16 + 8];
            if (z == 0) {
                size_t base = (size_t)(m0 + wm + mt * 16 + l16) * GN + n0 + wn + quad * 16;
                *(u16x8*)&Cb[base]     = va;
                *(u16x8*)&Cb[base + 8] = vb;
            } else {
                // K half-split: dk = quad*16 + c -> half ks = quad>>1, within = (quad&1)*16 + c
                size_t base = tb + (size_t)(quad >> 1) * 2048
                            + (size_t)(mt * 16 + l16) * 32 + (quad & 1) * 16;
                *(u16x8*)&Cb[base]     = va;
                *(u16x8*)&Cb[base + 8] = vb;
            }
        }
    } else {
        // V: VT[h][kb][ks][dv][32'], kappa within each 32-key half
        for (int mt = 0; mt < 4; mt++) {
            float o0[4], o1[4];
            for (int r = 0; r < 4; r++) {
                int m = m0 + wm + mt * 16 + quad * 4 + r;
                float v0 = acc[mt][0][r];
                float v1 = acc[mt][1][r];
                float s0, c0, s1, c1;
                if (csT) {
                    c0 = csT[m * 32 + l16];      s0 = snT[m * 32 + l16];
                    c1 = csT[m * 32 + 16 + l16]; s1 = snT[m * 32 + 16 + l16];
                } else {
                    __sincosf(freqs[m * 32 + l16], &s0, &c0);
                    __sincosf(freqs[m * 32 + 16 + l16], &s1, &c1);
                }
                o0[r] = v0 * c0 - v1 * s0;
                o1[r] = v1 * c1 + v0 * s1;
            }
            const int ks = mt >> 1;                       // key half
            const int sl = 4 * (mt & 1) + 8 * quad;       // slot within half (r adds 0..3)
            const size_t hb = tb + (size_t)ks * 2048 + sl;
            u16x4 u;
            u = { f32_to_bf16(o0[0]), f32_to_bf16(o0[1]), f32_to_bf16(o0[2]), f32_to_bf16(o0[3]) };
            *(u16x4*)&Cb[hb + (size_t)l16 * 32] = u;
            u = { f32_to_bf16(o1[0]), f32_to_bf16(o1[1]), f32_to_bf16(o1[2]), f32_to_bf16(o1[3]) };
            *(u16x4*)&Cb[hb + (size_t)(16 + l16) * 32] = u;
            u = { f32_to_bf16(acc[mt][2][0]), f32_to_bf16(acc[mt][2][1]),
                  f32_to_bf16(acc[mt][2][2]), f32_to_bf16(acc[mt][2][3]) };
            *(u16x4*)&Cb[hb + (size_t)(32 + l16) * 32] = u;
            u = { f32_to_bf16(acc[mt][3][0]), f32_to_bf16(acc[mt][3][1]),
                  f32_to_bf16(acc[mt][3][2]), f32_to_bf16(acc[mt][3][3]) };
            *(u16x4*)&Cb[hb + (size_t)(48 + l16) * 32] = u;
        }
    }
}

// ---------------------------------------------------------------------------
// Output projection GEMM. Tile 64x128, grid (64 m, 8 n) = 512 blocks = 2/CU.
// Single-barrier double-buffer protocol (round-12 verified).
// ---------------------------------------------------------------------------
__global__ __launch_bounds__(256) void gemm_out(
    const u16* __restrict__ A, const u16* __restrict__ W, float* __restrict__ C)
{
    __shared__ u16 SM[12288];  // [buf][ A 2048 | B 4096 ] u16, double-buffered

    const int tid  = threadIdx.x;
    const int w    = tid >> 6;
    const int lane = tid & 63;
    const int quad = lane >> 4;
    const int l16  = lane & 15;
    const int m0 = blockIdx.x * 64;
    const int n0 = blockIdx.y * 128;
    const int wm = (w >> 1) * 32;
    const int wn = (w & 1) * 64;

    const int sr = tid >> 2;
    const int sc = (((tid & 3) ^ ((tid >> 3) & 3))) * 8;   // swizzled source chunk
    const size_t aoff  = (size_t)(m0 + sr) * GK + sc;
    const size_t boff0 = (size_t)(n0 + sr) * GK + sc;
    const size_t boff1 = boff0 + (size_t)64 * GK;

    const int csw = (quad ^ ((l16 >> 1) & 3)) * 8;

    f32x4 acc[2][4];
    for (int i = 0; i < 2; i++)
        for (int j = 0; j < 4; j++) acc[i][j] = 0.f;

    // prologue: stage tile 0 -> buf 0
    {
        u16* Ab = SM;
        gl_lds16(A + aoff,  &Ab[w * 512]);
        gl_lds16(W + boff0, &Ab[2048 + w * 512]);
        gl_lds16(W + boff1, &Ab[2048 + 2048 + w * 512]);
    }

    for (int it = 0; it < 32; ++it) {
        __syncthreads();   // DMA for tile it drained; buf^1 free
        if (it < 31) {
            const int k0 = (it + 1) * 32;
            u16* Ab = SM + ((it + 1) & 1) * 6144;
            gl_lds16(A + aoff + k0,  &Ab[w * 512]);
            gl_lds16(W + boff0 + k0, &Ab[2048 + w * 512]);
            gl_lds16(W + boff1 + k0, &Ab[2048 + 2048 + w * 512]);
        }
        const u16* As = SM + (it & 1) * 6144;
        const u16* Bs = As + 2048;

        bf16x8 af[2], bfr[4];
        for (int t = 0; t < 2; t++)
            af[t] = *(const bf16x8*)&As[(wm + t * 16 + l16) * 32 + csw];
        for (int t = 0; t < 4; t++)
            bfr[t] = *(const bf16x8*)&Bs[(wn + t * 16 + l16) * 32 + csw];
        for (int mt = 0; mt < 2; mt++)
            for (int nt = 0; nt < 4; nt++)
                acc[mt][nt] = __builtin_amdgcn_mfma_f32_16x16x32_bf16(
                    af[mt], bfr[nt], acc[mt][nt], 0, 0, 0);
    }
    __syncthreads();   // all compute done; SM dead -> reusable as scratch

    // per-wave fp32 transpose scratch: 16 rows x 68 floats
    float* tr = (float*)SM + w * 1088;
    for (int mt = 0; mt < 2; mt++) {
        #pragma unroll
        for (int nt = 0; nt < 4; nt++)
            #pragma unroll
            for (int r = 0; r < 4; r++)
                tr[(quad * 4 + r) * 68 + nt * 16 + l16] = acc[mt][nt][r];
        size_t base = (size_t)(m0 + wm + mt * 16 + l16) * GN + n0 + wn + quad * 16;
        #pragma unroll
        for (int c = 0; c < 4; c++) {
            f32x4 v = *(const f32x4*)&tr[l16 * 68 + quad * 16 + c * 4];
            *(f32x4*)&C[base + c * 4] = v;
        }
    }
}

// ---------------------------------------------------------------------------
// Flash attention, causal. One block per (head, 64-row q-block): grid 1024,
// long blocks (qb large) dispatched FIRST (qb = 63 - (id>>4)) so the
// hardware scheduler backfills short ones -> dynamic load balance.
// LDS 50176 B (KV dbuf 32768 + dedicated EX 17408) -> 3 blocks/CU
// (__launch_bounds__(256,3)). 4-wave 2-D split is the MEASURED OPTIMUM:
// 8-wave split (R14: 60.0us, barrier-rendezvous-bound), 4-resident variants
// (R7/8/9: nondeterministic failures) are both worse — do not retry.
// Per-iteration body: 2-D wave split (wave owns 32q x 32k), exp2-domain
// softmax (Q pre-scaled by 0.125*log2e, -16*log2e seeded in the QK
// accumulator), denominator via ones-MFMA, K/V double-buffered via
// global_load_lds, one barrier/iter.
// XCD locality: h = (id&7)*2 + ((id>>3)&1) keeps 2 heads (2MB KV) per XCD L2.
// ---------------------------------------------------------------------------
__global__ __launch_bounds__(256, 3) void attn_kernel(
    const u16* __restrict__ Qb, const u16* __restrict__ KT,
    const u16* __restrict__ VTg, u16* __restrict__ valsb)
{
    __shared__ __align__(16) u16 KV[2][8192];   // [buf][ K 4096 | V 4096 ] u16
    __shared__ __align__(16) float EX[4352];    // exchange / transpose scratch

    const int tid  = threadIdx.x;
    const int w    = tid >> 6;
    const int lane = tid & 63;
    const int quad = lane >> 4;
    const int l16  = lane & 15;
    const int HD = 1024;

    const int id = blockIdx.x;
    const int h  = (id & 7) * 2 + ((id >> 3) & 1);   // 2 heads per XCD -> L2-local KV
    const int qb = 63 - (id >> 4);                   // long blocks first

    const u16* kt = KT  + (size_t)h * 262144;
    const u16* vt = VTg + (size_t)h * 262144;

    const int wq = w >> 1;     // q half owned (32 rows)
    const int wk = w & 1;      // key half owned (32 keys)

    // swizzled per-lane DMA source offset within a 1KB (16-row) span
    const int dmaoff = (lane >> 2) * 32 + ((lane & 3) ^ ((lane >> 3) & 3)) * 8;
    const int csw = (quad ^ ((l16 >> 1) & 3)) * 8;   // swizzled read chunk

    // ones A-fragment for the denominator MFMA
    bf16x8 ones;
    #pragma unroll
    for (int i = 0; i < 8; i++) ones[i] = (short)0x3F80;   // bf16 1.0
    const f32x4 seed = { -23.0831204f, -23.0831204f, -23.0831204f, -23.0831204f };

    // Q B-frags for this wave's 32 q rows (2 groups x 2 dk halves)
    bf16x8 bq[2][2];
    #pragma unroll
    for (int qt = 0; qt < 2; qt++) {
        const size_t qrow = (size_t)(qb * 64 + wq * 32 + qt * 16 + l16);
        bq[qt][0] = *(const bf16x8*)&Qb[qrow * HD + h * 64 + quad * 8];
        bq[qt][1] = *(const bf16x8*)&Qb[qrow * HD + h * 64 + 32 + quad * 8];
    }

    f32x4 o[2][4];
    #pragma unroll
    for (int i = 0; i < 2; i++)
        #pragma unroll
        for (int j = 0; j < 4; j++) o[i][j] = 0.f;
    f32x4 ls_acc[2];
    ls_acc[0] = 0.f;
    ls_acc[1] = 0.f;

    // prologue DMA: tile 0 -> buf 0
    #pragma unroll
    for (int i = 0; i < 2; i++) {
        gl_lds16(kt + i * 2048 + w * 512 + dmaoff, &KV[0][i * 2048 + w * 512]);
        gl_lds16(vt + i * 2048 + w * 512 + dmaoff, &KV[0][4096 + i * 2048 + w * 512]);
    }

    for (int kb = 0; kb <= qb; kb++) {
        __syncthreads();  // DMA for kb drained; buf[(kb+1)&1] free
        if (kb < qb) {
            const int nb = (kb + 1) & 1;
            const u16* ksrc = kt + (size_t)(kb + 1) * 4096;
            const u16* vsrc = vt + (size_t)(kb + 1) * 4096;
            #pragma unroll
            for (int i = 0; i < 2; i++) {
                gl_lds16(ksrc + i * 2048 + w * 512 + dmaoff, &KV[nb][i * 2048 + w * 512]);
                gl_lds16(vsrc + i * 2048 + w * 512 + dmaoff, &KV[nb][4096 + i * 2048 + w * 512]);
            }
        }
        const u16* Ksb = &KV[kb & 1][0];
        const u16* Vsb = &KV[kb & 1][4096];

        // K frags: only this wave's 32-key half (both dk halves)
        bf16x8 ak[2][2];
        #pragma unroll
        for (int kt2 = 0; kt2 < 2; kt2++) {
            const int krow = wk * 32 + kt2 * 16 + l16;
            ak[kt2][0] = *(const bf16x8*)&Ksb[krow * 32 + csw];
            ak[kt2][1] = *(const bf16x8*)&Ksb[2048 + krow * 32 + csw];
        }

        // S^T = K * Q^T (exp2 domain, bias seeded into accumulator)
        f32x4 s[2][2];
        #pragma unroll
        for (int qt = 0; qt < 2; qt++)
            #pragma unroll
            for (int kt2 = 0; kt2 < 2; kt2++) {
                f32x4 z4 = seed;
                z4 = __builtin_amdgcn_mfma_f32_16x16x32_bf16(ak[kt2][0], bq[qt][0], z4, 0, 0, 0);
                s[qt][kt2] = __builtin_amdgcn_mfma_f32_16x16x32_bf16(ak[kt2][1], bq[qt][1], z4, 0, 0, 0);
            }

        if (kb == qb) {  // diagonal: mask key > q
            #pragma unroll
            for (int qt = 0; qt < 2; qt++)
                #pragma unroll
                for (int kt2 = 0; kt2 < 2; kt2++)
                    #pragma unroll
                    for (int r = 0; r < 4; r++)
                        if (wk * 32 + kt2 * 16 + quad * 4 + r > wq * 32 + qt * 16 + l16)
                            s[qt][kt2][r] = -1e30f;
        }

        // V frags (this wave's key half) issued before exp so lgkmcnt hides
        bf16x8 av[4];
        #pragma unroll
        for (int nv = 0; nv < 4; nv++)
            av[nv] = *(const bf16x8*)&Vsb[wk * 2048 + (nv * 16 + l16) * 32 + csw];

        // p = exp2(s): one v_exp_f32 per element, no prologue VALU
        #pragma unroll
        for (int qt = 0; qt < 2; qt++)
            #pragma unroll
            for (int kt2 = 0; kt2 < 2; kt2++)
                #pragma unroll
                for (int r = 0; r < 4; r++)
                    s[qt][kt2][r] = EXP2(s[qt][kt2][r]);

        bf16x8 bp[2];
        #pragma unroll
        for (int qt = 0; qt < 2; qt++) {
            bf16x8 b = { f32_to_bf16_trunc(s[qt][0][0]), f32_to_bf16_trunc(s[qt][0][1]),
                         f32_to_bf16_trunc(s[qt][0][2]), f32_to_bf16_trunc(s[qt][0][3]),
                         f32_to_bf16_trunc(s[qt][1][0]), f32_to_bf16_trunc(s[qt][1][1]),
                         f32_to_bf16_trunc(s[qt][1][2]), f32_to_bf16_trunc(s[qt][1][3]) };
            bp[qt] = b;
        }

        // denominator via matrix pipe: ls_acc[qt] += ones x P
        #pragma unroll
        for (int qt = 0; qt < 2; qt++)
            ls_acc[qt] = __builtin_amdgcn_mfma_f32_16x16x32_bf16(
                ones, bp[qt], ls_acc[qt], 0, 0, 0);

        // 8 independent accumulator chains
        #pragma unroll
        for (int nv = 0; nv < 4; nv++)
            #pragma unroll
            for (int qt = 0; qt < 2; qt++)
                o[qt][nv] = __builtin_amdgcn_mfma_f32_16x16x32_bf16(
                    av[nv], bp[qt], o[qt][nv], 0, 0, 0);
    }

    // ---- epilogue: combine key-half partials across the wave pair ----
    // ls_acc rows are all identical (ones x P) -> per-lane denominator
    // for q row l16 of group qt is ls_acc[qt][0]; no shfl needed.
    const float lsum0 = ls_acc[0][0];
    const float lsum1 = ls_acc[1][0];

    // wave keeps q-group wk, sends q-group wk^1 to partner wave (w^1).
    // All register indices static (wave-uniform branch on wk).
    float* my = EX + (w * 64 + lane) * 17;
    if (wk == 0) {
        #pragma unroll
        for (int nv = 0; nv < 4; nv++) *(f32x4*)&my[nv * 4] = o[1][nv];
        my[16] = lsum1;
    } else {
        #pragma unroll
        for (int nv = 0; nv < 4; nv++) *(f32x4*)&my[nv * 4] = o[0][nv];
        my[16] = lsum0;
    }
    __syncthreads();   // exchange visible
    const float* pr = EX + ((w ^ 1) * 64 + lane) * 17;
    f32x4 fin[4];
    float denom;
    if (wk == 0) {
        #pragma unroll
        for (int nv = 0; nv < 4; nv++) fin[nv] = o[0][nv] + *(const f32x4*)&pr[nv * 4];
        denom = lsum0 + pr[16];
    } else {
        #pragma unroll
        for (int nv = 0; nv < 4; nv++) fin[nv] = o[1][nv] + *(const f32x4*)&pr[nv * 4];
        denom = lsum1 + pr[16];
    }
    const float inv = 1.f / denom;
    __syncthreads();   // exchange reads done; EX reusable as scratch

    // wave-private transpose scratch: 16 rows x 68 floats
    float* myOw = EX + w * 1088;
    #pragma unroll
    for (int nv = 0; nv < 4; nv++)
        #pragma unroll
        for (int r = 0; r < 4; r++)
            myOw[l16 * 68 + nv * 16 + quad * 4 + r] = fin[nv][r] * inv;
    #pragma unroll
    for (int i = 0; i < 4; i++) {
        int row = i * 4 + quad;   // q row within this wave's owned 16
        f32x4 vv = *(const f32x4*)&myOw[row * 68 + l16 * 4];
        u16x4 u = { f32_to_bf16(vv[0]), f32_to_bf16(vv[1]), f32_to_bf16(vv[2]), f32_to_bf16(vv[3]) };
        *(u16x4*)&valsb[(size_t)(qb * 64 + wq * 32 + wk * 16 + row) * HD + h * 64 + l16 * 4] = u;
    }
}

// ---------------------------------------------------------------------------
// ws layout (u16 idx): qc 0 | kc 4M | vc 8M | wqc 12M | wkc 13M | wvc 14M |
// woc 15M | Qb 16M | KT 20M | VT 24M | trig tables 28M (if ws allows).
// valsb reuses qc. Base 56 MiB + 1 MiB tables.
// ---------------------------------------------------------------------------
extern "C" void kernel_launch(void* const* d_in, const int* in_sizes, int n_in,
                              void* d_out, int out_size, void* d_ws, size_t ws_size,
                              hipStream_t stream) {
    const float* q     = (const float*)d_in[0];
    const float* k     = (const float*)d_in[1];
    const float* v     = (const float*)d_in[2];
    const float* freqs = (const float*)d_in[4];
    const float* wq    = (const float*)d_in[5];
    const float* wk    = (const float*)d_in[6];
    const float* wv    = (const float*)d_in[7];
    const float* wo    = (const float*)d_in[8];

    u16* B = (u16*)d_ws;
    u16* qc  = B;
    u16* kc  = B + (size_t)4194304;
    u16* vc  = B + (size_t)8388608;
    u16* wqc = B + (size_t)12582912;
    u16* wkc = B + (size_t)13631488;
    u16* wvc = B + (size_t)14680064;
    u16* woc = B + (size_t)15728640;
    u16* Qb  = B + (size_t)16777216;
    u16* KT  = B + (size_t)20971520;
    u16* VT  = B + (size_t)25165824;
    u16* valsb = qc;   // qc dead after gemm_rope reads it

    // trig tables after VT: cos [131072 floats] then sin [131072 floats]
    const size_t tab_off_u16 = 29360128;                 // byte 58720256
    const size_t need_bytes  = 58720256 + 2 * 131072 * sizeof(float);
    float* csT = (ws_size >= need_bytes) ? (float*)(B + tab_off_u16) : (float*)0;

    CastArgs ca;
    ca.src[0] = q;  ca.dst[0] = qc;  ca.n4[0] = 1048576;
    ca.src[1] = k;  ca.dst[1] = kc;  ca.n4[1] = 1048576;
    ca.src[2] = v;  ca.dst[2] = vc;  ca.n4[2] = 1048576;
    ca.src[3] = wq; ca.dst[3] = wqc; ca.n4[3] = 262144;
    ca.src[4] = wk; ca.dst[4] = wkc; ca.n4[4] = 262144;
    ca.src[5] = wv; ca.dst[5] = wvc; ca.n4[5] = 262144;
    ca.src[6] = wo; ca.dst[6] = woc; ca.n4[6] = 262144;
    ca.src[7] = freqs; ca.dst[7] = (u16*)csT; ca.n4[7] = csT ? 32768 : 0;
    cast_kernel<<<dim3(1024, 8), 256, 0, stream>>>(ca);

    gemm_rope<<<dim3(32, 8, 3), 256, 0, stream>>>(
        qc, kc, vc, wqc, wkc, wvc, Qb, KT, VT, freqs, csT);

    attn_kernel<<<dim3(1024), 256, 0, stream>>>(Qb, KT, VT, valsb);

    gemm_out<<<dim3(64, 8), 256, 0, stream>>>(valsb, woc, (float*)d_out);
}